// Round 11
// baseline (718.715 us; speedup 1.0000x reference)
//
#include <hip/hip_runtime.h>
#include <float.h>
#include <stdint.h>

// Problem constants (h=1, b=32, n=2048, d=256, c=2048)
#define N_TOK 65536
#define DIM   256
#define CODES 2048
#define DECAY 0.8f
#define EPSV  1e-5f

// Output offsets (floats) in d_out, concatenated in reference return order
#define OUT_Q    ((size_t)0)            // quantize: 16777216
#define OUT_IND  ((size_t)16777216)     // embed_ind: 65536 (written as float)
#define OUT_DIST ((size_t)16842752)     // dist: 134217728
#define OUT_NEMB ((size_t)151060480)    // new_embed: 524288
#define OUT_NCS  ((size_t)151584768)    // new_cluster_size: 2048
#define OUT_NEA  ((size_t)151586816)    // new_embed_avg: 524288

// Workspace layout (bytes)
#define WSB_KEYS ((size_t)0)         // u64[65536] = 524288
#define WSB_CNT  ((size_t)524288)    // int[2048] = 8192   (zeroed in k_prep)
#define WSB_CUR  ((size_t)532480)    // int[2048] = 8192   (zeroed in k_prep)
#define WSB_OFF  ((size_t)540672)    // int[2048] = 8192
#define WSB_LIST ((size_t)548864)    // int[65536] = 262144
#define WSB_EHI  ((size_t)811008)    // ushort[524288] = 1048576
#define WSB_ELO  ((size_t)1859584)   // ushort[524288] = 1048576
#define WSB_X2   ((size_t)2908160)   // f32[65536] = 262144
#define WSB_E2   ((size_t)3170304)   // f32[2048] = 8192
#define WSB_SMOO ((size_t)3178496)   // f32[2048] = 8192

typedef __attribute__((ext_vector_type(8))) short bf16x8;
typedef __attribute__((ext_vector_type(4))) float f32x4;

#define MFMA(a, b, c) __builtin_amdgcn_mfma_f32_16x16x32_bf16(a, b, c, 0, 0, 0)

typedef const unsigned int __attribute__((address_space(1)))* as1_u32p;
typedef unsigned int __attribute__((address_space(3)))* as3_u32p;

__device__ __forceinline__ void async_copy16(const void* g, void* l) {
    __builtin_amdgcn_global_load_lds((as1_u32p)g, (as3_u32p)l, 16, 0, 0);
}

__device__ __forceinline__ unsigned short f2bf(float f) {
    unsigned u = __float_as_uint(f);
    unsigned r = (u + 0x7FFFu + ((u >> 16) & 1u)) >> 16;   // RN-even
    return (unsigned short)r;
}
__device__ __forceinline__ float bf2f(unsigned short s) {
    return __uint_as_float(((unsigned)s) << 16);
}

// ------- prep: split x AND embed to bf16 hi/lo + row |.|^2 + init keys/cnt ---
// one wave per TWO rows (2 independent load/convert/store chains for ILP).
__global__ void k_prep(const float* __restrict__ x, const float* __restrict__ embed,
                       unsigned short* __restrict__ xhi, unsigned short* __restrict__ xlo,
                       unsigned short* __restrict__ ehi, unsigned short* __restrict__ elo,
                       float* __restrict__ x2, float* __restrict__ e2,
                       unsigned long long* __restrict__ keys, int* __restrict__ cntcur) {
    int gid = blockIdx.x * blockDim.x + threadIdx.x;
    if (gid < 4096) cntcur[gid] = 0;                 // cnt + cursor zero
    int wv = gid >> 6;
    int l  = gid & 63;
    #pragma unroll
    for (int half = 0; half < 2; ++half) {
        int r = wv * 2 + half;
        const float* src;
        unsigned short *hi, *lo;
        float* sq;
        int rr;
        if (r < N_TOK) {
            src = x; hi = xhi; lo = xlo; sq = x2; rr = r;
            if (l == 0) keys[r] = 0xFFFFFFFFFFFFFFFFULL;  // argmin key = +inf
        } else {
            src = embed; hi = ehi; lo = elo; sq = e2; rr = r - N_TOK;
        }
        float4 v = reinterpret_cast<const float4*>(src + (size_t)rr * DIM)[l];
        ushort4 h, w;
        h.x = f2bf(v.x); h.y = f2bf(v.y); h.z = f2bf(v.z); h.w = f2bf(v.w);
        w.x = f2bf(v.x - bf2f(h.x));
        w.y = f2bf(v.y - bf2f(h.y));
        w.z = f2bf(v.z - bf2f(h.z));
        w.w = f2bf(v.w - bf2f(h.w));
        reinterpret_cast<ushort4*>(hi + (size_t)rr * DIM)[l] = h;
        reinterpret_cast<ushort4*>(lo + (size_t)rr * DIM)[l] = w;
        float s = v.x * v.x + v.y * v.y + v.z * v.z + v.w * v.w;
        #pragma unroll
        for (int m = 32; m >= 1; m >>= 1) s += __shfl_xor(s, m);
        if (l == 0) sq[rr] = s;
    }
}

// ---------------- main: 3-pass split-bf16 MFMA GEMM + dist + argmin ----------
// 128x128 tile, 4 waves (2x2 of 64x64), BK=32, K=256 (8 steps).
// SINGLE-buffered LDS (32 KB) -> 5 blocks/CU (LDS was the occupancy limiter:
// dbuf 64 KB capped at 2 blocks/CU = 2 waves/SIMD, leaving barrier drains
// exposed; 5 staggered blocks/CU give cross-block wave overlap [m114]).
// Per step: stage -> syncthreads(drain) -> ds_read+MFMA -> syncthreads.
// Chunk swizzle (conflict-free, validated r5+), XCD swizzle (r6), 3-pass (r7).
__launch_bounds__(256)
__global__ void k_main(const unsigned short* __restrict__ xhi, const unsigned short* __restrict__ xlo,
                       const unsigned short* __restrict__ ehi, const unsigned short* __restrict__ elo,
                       const float* __restrict__ x2, const float* __restrict__ e2,
                       float* __restrict__ dist, unsigned long long* __restrict__ keys) {
    __shared__ unsigned short lds[4][128][32];   // {Ahi,Alo,Bhi,Blo} x 8KB = 32 KB
    const int tid = threadIdx.x;
    const int l   = tid & 63;
    const int wid = tid >> 6;
    const int wm  = wid >> 1, wn = wid & 1;

    // T1: XCD swizzle (FETCH 265 MB -> 41.6 MB, validated r6).
    const int n   = blockIdx.x;
    const int w_  = (n & 7) * 1024 + (n >> 3);
    const int bx  = w_ & 15;        // code-tile (16)
    const int by  = w_ >> 4;        // token-tile (512)
    const int t0  = by * 128;
    const int c0  = bx * 128;

    const unsigned short* gsrc = (wid == 0) ? xhi : (wid == 1) ? xlo : (wid == 2) ? ehi : elo;
    const int r0 = (wid < 2) ? t0 : c0;

    // chunk pre-swizzle: lane l stages LDS slot (l&3) of row (l>>2)+16i; data
    // landing there is global chunk (l&3)^((l>>3)&3)  (validated r5-r10).
    const int swc = ((l & 3) ^ ((l >> 3) & 3)) * 8;
    const unsigned short* gstage = gsrc + (size_t)(r0 + (l >> 2)) * DIM + swc;

    f32x4 acc[4][4];
    #pragma unroll
    for (int i = 0; i < 4; ++i)
        #pragma unroll
        for (int j = 0; j < 4; ++j) acc[i][j] = (f32x4){0.f, 0.f, 0.f, 0.f};

    const int kg = l >> 4;     // k-group 0..3
    const int lr = l & 15;
    const int ks = (kg ^ ((lr >> 1) & 3)) * 8;   // swizzled slot (shorts) for reads

    for (int step = 0; step < 8; ++step) {
        // stage this K-step (32 KB across 4 waves)
        {
            const unsigned short* g = gstage + (size_t)step * 32;
            unsigned short* lb = &lds[wid][0][0];
            #pragma unroll
            for (int i = 0; i < 8; ++i)
                async_copy16(g + (size_t)i * 16 * DIM, lb + i * 512);
        }
        __syncthreads();   // drains vmcnt: tile visible (drain hidden by other blocks on CU)

        bf16x8 ah[4], al[4], bh[4], bl[4];
        #pragma unroll
        for (int f = 0; f < 4; ++f) {
            ah[f] = *(const bf16x8*)&lds[0][wm * 64 + f * 16 + lr][ks];
            al[f] = *(const bf16x8*)&lds[1][wm * 64 + f * 16 + lr][ks];
            bh[f] = *(const bf16x8*)&lds[2][wn * 64 + f * 16 + lr][ks];
            bl[f] = *(const bf16x8*)&lds[3][wn * 64 + f * 16 + lr][ks];
        }
        __builtin_amdgcn_s_setprio(1);
        // pass-outer: 16 independent acc chains per pass
        #pragma unroll
        for (int mf = 0; mf < 4; ++mf)
            #pragma unroll
            for (int nf = 0; nf < 4; ++nf)
                acc[mf][nf] = MFMA(al[mf], bh[nf], acc[mf][nf]);   // xl*eh
        #pragma unroll
        for (int mf = 0; mf < 4; ++mf)
            #pragma unroll
            for (int nf = 0; nf < 4; ++nf)
                acc[mf][nf] = MFMA(ah[mf], bl[nf], acc[mf][nf]);   // xh*el
        #pragma unroll
        for (int mf = 0; mf < 4; ++mf)
            #pragma unroll
            for (int nf = 0; nf < 4; ++nf)
                acc[mf][nf] = MFMA(ah[mf], bh[nf], acc[mf][nf]);   // xh*eh
        __builtin_amdgcn_s_setprio(0);
        if (step < 7) __syncthreads();   // all reads done before next stage overwrites
    }

    float e2v[4];
    #pragma unroll
    for (int nf = 0; nf < 4; ++nf) e2v[nf] = e2[c0 + wn * 64 + nf * 16 + lr];

    #pragma unroll
    for (int mf = 0; mf < 4; ++mf) {
        #pragma unroll
        for (int reg = 0; reg < 4; ++reg) {
            int t = t0 + wm * 64 + mf * 16 + kg * 4 + reg;     // D row = (lane>>4)*4 + reg
            float tx2 = x2[t];
            float bs = FLT_MAX;
            int   bc = 0;
            #pragma unroll
            for (int nf = 0; nf < 4; ++nf) {
                int c = c0 + wn * 64 + nf * 16 + lr;           // D col = lane&15
                float sq = fmaxf(tx2 + e2v[nf] - 2.0f * acc[mf][nf][reg], 0.0f);
                __builtin_nontemporal_store(-sqrtf(sq), dist + (size_t)t * CODES + c);
                if (sq < bs) { bs = sq; bc = c; }
            }
            #pragma unroll
            for (int m = 8; m >= 1; m >>= 1) {
                float os = __shfl_xor(bs, m);
                int   oc = __shfl_xor(bc, m);
                if (os < bs || (os == bs && oc < bc)) { bs = os; bc = oc; }
            }
            if (lr == 0) {
                unsigned long long key = ((unsigned long long)__float_as_uint(bs) << 32) | (unsigned)bc;
                atomicMin(keys + t, key);
            }
        }
    }
}

// -------- quantize gather + ind write + count: one wave per TWO tokens -------
__global__ void k_qcount(const float* __restrict__ embed, const unsigned long long* __restrict__ keys,
                         float* __restrict__ q, float* __restrict__ ind_f, int* __restrict__ cnt) {
    int gid  = blockIdx.x * blockDim.x + threadIdx.x;
    int wv   = gid >> 6;
    int lane = threadIdx.x & 63;
    int w0 = wv * 2;
    if (w0 >= N_TOK) return;
    int c0 = (int)(keys[w0] & 0xFFFFFFFFULL);
    int c1 = (int)(keys[w0 + 1] & 0xFFFFFFFFULL);
    f32x4 e0 = reinterpret_cast<const f32x4*>(embed + (size_t)c0 * DIM)[lane];
    f32x4 e1 = reinterpret_cast<const f32x4*>(embed + (size_t)c1 * DIM)[lane];
    __builtin_nontemporal_store(e0, reinterpret_cast<f32x4*>(q + (size_t)w0 * DIM) + lane);
    __builtin_nontemporal_store(e1, reinterpret_cast<f32x4*>(q + (size_t)(w0 + 1) * DIM) + lane);
    if (lane == 0) {
        ind_f[w0] = (float)c0;
        ind_f[w0 + 1] = (float)c1;
        atomicAdd(cnt + c0, 1);
        atomicAdd(cnt + c1, 1);
    }
}

// ---------------- scan: offsets + new_cluster_size + smoothed (fused fin1) ---
__global__ void k_scan(const int* __restrict__ cnt, const float* __restrict__ cs,
                       int* __restrict__ offsets, float* __restrict__ out_ncs,
                       float* __restrict__ smoothed) {
    __shared__ int red[256];
    __shared__ float fred[256];
    __shared__ float s_total;
    int t = threadIdx.x;
    int c8[8];
    int own = 0;
    float ncs8[8];
    float fpart = 0.f;
    #pragma unroll
    for (int r = 0; r < 8; ++r) {
        int c = t * 8 + r;
        int v = cnt[c];
        c8[r] = v;
        own += v;
        float nn = cs[c] * DECAY + (float)v * (1.0f - DECAY);
        out_ncs[c] = nn;
        ncs8[r] = nn;
        fpart += nn;
    }
    red[t] = own;
    fred[t] = fpart;
    __syncthreads();
    for (int d = 1; d < 256; d <<= 1) {
        int v = (t >= d) ? red[t - d] : 0;
        __syncthreads();
        red[t] += v;
        __syncthreads();
    }
    for (int s = 128; s >= 1; s >>= 1) {
        if (t < s) fred[t] += fred[t + s];
        __syncthreads();
    }
    if (t == 0) s_total = fred[0];
    __syncthreads();
    int base = red[t] - own;
    float total = s_total;
    float denom = total + (float)CODES * EPSV;
    #pragma unroll
    for (int r = 0; r < 8; ++r) {
        int c = t * 8 + r;
        offsets[c] = base;
        base += c8[r];
        smoothed[c] = (ncs8[r] + EPSV) / denom * total;
    }
}

// ---------------- scatter token ids into per-code buckets --------------------
__global__ void k_scatter(const unsigned long long* __restrict__ keys,
                          const int* __restrict__ offsets, int* __restrict__ cursor,
                          int* __restrict__ list) {
    int t = blockIdx.x * blockDim.x + threadIdx.x;
    if (t >= N_TOK) return;
    int c = (int)(keys[t] & 0xFFFFFFFFULL);
    int pos = atomicAdd(cursor + c, 1);
    list[offsets[c] + pos] = t;
}

// ---------------- per-code sum of x rows + fused fin2 ------------------------
__global__ void k_esum(const float* __restrict__ x, const int* __restrict__ cnt,
                       const int* __restrict__ offsets, const int* __restrict__ list,
                       const float* __restrict__ ea, const float* __restrict__ smoothed,
                       float* __restrict__ out_nea, float* __restrict__ out_nemb) {
    __shared__ f32x4 part[8][64];
    int c    = blockIdx.x;
    int tid  = threadIdx.x;
    int w    = tid >> 6;
    int lane = tid & 63;
    int n    = cnt[c];
    int off  = offsets[c];
    f32x4 s = (f32x4){0.f, 0.f, 0.f, 0.f};
    for (int i = w; i < n; i += 8) {
        int t = list[off + i];
        s += reinterpret_cast<const f32x4*>(x + (size_t)t * DIM)[lane];
    }
    part[w][lane] = s;
    __syncthreads();
    if (w == 0) {
        f32x4 tot = part[0][lane];
        #pragma unroll
        for (int p = 1; p < 8; ++p) tot += part[p][lane];
        size_t idx = (size_t)c * DIM + lane * 4;
        f32x4 ea4 = *reinterpret_cast<const f32x4*>(ea + idx);
        f32x4 nea;
        float inv = 1.0f / smoothed[c];
        #pragma unroll
        for (int j = 0; j < 4; ++j) nea[j] = ea4[j] * DECAY + tot[j] * (1.0f - DECAY);
        *reinterpret_cast<f32x4*>(out_nea + idx) = nea;
        f32x4 nemb;
        #pragma unroll
        for (int j = 0; j < 4; ++j) nemb[j] = nea[j] * inv;
        *reinterpret_cast<f32x4*>(out_nemb + idx) = nemb;
    }
}

extern "C" void kernel_launch(void* const* d_in, const int* in_sizes, int n_in,
                              void* d_out, int out_size, void* d_ws, size_t ws_size,
                              hipStream_t stream) {
    const float* x     = (const float*)d_in[0];
    const float* embed = (const float*)d_in[1];
    const float* eavg  = (const float*)d_in[2];
    const float* csz   = (const float*)d_in[3];
    float* out = (float*)d_out;
    char*  wsb = (char*)d_ws;

    unsigned long long* keys = (unsigned long long*)(wsb + WSB_KEYS);
    int*            cnt  = (int*)(wsb + WSB_CNT);     // cnt+cur contiguous 16KB
    int*            cur  = (int*)(wsb + WSB_CUR);
    int*            off  = (int*)(wsb + WSB_OFF);
    int*            list = (int*)(wsb + WSB_LIST);
    unsigned short* ehi  = (unsigned short*)(wsb + WSB_EHI);
    unsigned short* elo  = (unsigned short*)(wsb + WSB_ELO);
    float*          x2   = (float*)(wsb + WSB_X2);
    float*          e2   = (float*)(wsb + WSB_E2);
    float*          smoo = (float*)(wsb + WSB_SMOO);

    // x hi/lo staged in the quantize output region (same byte size); k_qcount
    // overwrites it AFTER k_main has consumed it (stream-ordered).
    unsigned short* xhi = (unsigned short*)(out + OUT_Q);
    unsigned short* xlo = xhi + (size_t)N_TOK * DIM;

    k_prep<<<(N_TOK + CODES) * 32 / 256, 256, 0, stream>>>(
        x, embed, xhi, xlo, ehi, elo, x2, e2, keys, cnt);

    k_main<<<(CODES / 128) * (N_TOK / 128), 256, 0, stream>>>(
        xhi, xlo, ehi, elo, x2, e2, out + OUT_DIST, keys);

    k_qcount<<<N_TOK * 32 / 256, 256, 0, stream>>>(embed, keys, out + OUT_Q,
                                                   out + OUT_IND, cnt);
    k_scan<<<1, 256, 0, stream>>>(cnt, csz, off, out + OUT_NCS, smoo);
    k_scatter<<<N_TOK / 256, 256, 0, stream>>>(keys, off, cur, list);
    k_esum<<<CODES, 512, 0, stream>>>(x, cnt, off, list, eavg, smoo,
                                      out + OUT_NEA, out + OUT_NEMB);
}

// Round 12
// 563.535 us; speedup vs baseline: 1.2754x; 1.2754x over previous
//
#include <hip/hip_runtime.h>
#include <float.h>
#include <stdint.h>

// Problem constants (h=1, b=32, n=2048, d=256, c=2048)
#define N_TOK 65536
#define DIM   256
#define CODES 2048
#define DECAY 0.8f
#define EPSV  1e-5f

// Output offsets (floats) in d_out, concatenated in reference return order
#define OUT_Q    ((size_t)0)            // quantize: 16777216
#define OUT_IND  ((size_t)16777216)     // embed_ind: 65536 (written as float)
#define OUT_DIST ((size_t)16842752)     // dist: 134217728
#define OUT_NEMB ((size_t)151060480)    // new_embed: 524288
#define OUT_NCS  ((size_t)151584768)    // new_cluster_size: 2048
#define OUT_NEA  ((size_t)151586816)    // new_embed_avg: 524288

// Workspace layout (bytes)
#define WSB_KEYS ((size_t)0)         // u64[65536] = 524288
#define WSB_CNT  ((size_t)524288)    // int[2048] = 8192   (zeroed in k_prep)
#define WSB_CUR  ((size_t)532480)    // int[2048] = 8192   (zeroed in k_prep)
#define WSB_OFF  ((size_t)540672)    // int[2048] = 8192
#define WSB_LIST ((size_t)548864)    // int[65536] = 262144
#define WSB_EHI  ((size_t)811008)    // ushort[524288] = 1048576
#define WSB_ELO  ((size_t)1859584)   // ushort[524288] = 1048576
#define WSB_X2   ((size_t)2908160)   // f32[65536] = 262144
#define WSB_E2   ((size_t)3170304)   // f32[2048] = 8192
#define WSB_SMOO ((size_t)3178496)   // f32[2048] = 8192

typedef __attribute__((ext_vector_type(8))) short bf16x8;
typedef __attribute__((ext_vector_type(4))) float f32x4;

#define MFMA(a, b, c) __builtin_amdgcn_mfma_f32_16x16x32_bf16(a, b, c, 0, 0, 0)

typedef const unsigned int __attribute__((address_space(1)))* as1_u32p;
typedef unsigned int __attribute__((address_space(3)))* as3_u32p;

__device__ __forceinline__ void async_copy16(const void* g, void* l) {
    __builtin_amdgcn_global_load_lds((as1_u32p)g, (as3_u32p)l, 16, 0, 0);
}

__device__ __forceinline__ unsigned short f2bf(float f) {
    unsigned u = __float_as_uint(f);
    unsigned r = (u + 0x7FFFu + ((u >> 16) & 1u)) >> 16;   // RN-even
    return (unsigned short)r;
}
__device__ __forceinline__ float bf2f(unsigned short s) {
    return __uint_as_float(((unsigned)s) << 16);
}

// ------- prep: split x AND embed to bf16 hi/lo + row |.|^2 + init keys/cnt ---
// one wave per TWO rows (2 independent load/convert/store chains for ILP).
__global__ void k_prep(const float* __restrict__ x, const float* __restrict__ embed,
                       unsigned short* __restrict__ xhi, unsigned short* __restrict__ xlo,
                       unsigned short* __restrict__ ehi, unsigned short* __restrict__ elo,
                       float* __restrict__ x2, float* __restrict__ e2,
                       unsigned long long* __restrict__ keys, int* __restrict__ cntcur) {
    int gid = blockIdx.x * blockDim.x + threadIdx.x;
    if (gid < 4096) cntcur[gid] = 0;                 // cnt + cursor zero
    int wv = gid >> 6;
    int l  = gid & 63;
    #pragma unroll
    for (int half = 0; half < 2; ++half) {
        int r = wv * 2 + half;
        const float* src;
        unsigned short *hi, *lo;
        float* sq;
        int rr;
        if (r < N_TOK) {
            src = x; hi = xhi; lo = xlo; sq = x2; rr = r;
            if (l == 0) keys[r] = 0xFFFFFFFFFFFFFFFFULL;  // argmin key = +inf
        } else {
            src = embed; hi = ehi; lo = elo; sq = e2; rr = r - N_TOK;
        }
        float4 v = reinterpret_cast<const float4*>(src + (size_t)rr * DIM)[l];
        ushort4 h, w;
        h.x = f2bf(v.x); h.y = f2bf(v.y); h.z = f2bf(v.z); h.w = f2bf(v.w);
        w.x = f2bf(v.x - bf2f(h.x));
        w.y = f2bf(v.y - bf2f(h.y));
        w.z = f2bf(v.z - bf2f(h.z));
        w.w = f2bf(v.w - bf2f(h.w));
        reinterpret_cast<ushort4*>(hi + (size_t)rr * DIM)[l] = h;
        reinterpret_cast<ushort4*>(lo + (size_t)rr * DIM)[l] = w;
        float s = v.x * v.x + v.y * v.y + v.z * v.z + v.w * v.w;
        #pragma unroll
        for (int m = 32; m >= 1; m >>= 1) s += __shfl_xor(s, m);
        if (l == 0) sq[rr] = s;
    }
}

// ---------------- main: 3-pass split-bf16 MFMA GEMM + dist + argmin ----------
// K-loop = r7 structure verbatim (dbuf + __syncthreads, chunk swizzle, XCD
// swizzle, 3-pass). NEW EPILOGUE: per-wave LDS transpose so dist stores are
// dwordx4 in 128B FULL-LINE segments (old scalar stores = 64B half-line NT
// partials -> measured 1.4 TB/s write wall = entire kernel duration).
__launch_bounds__(256)
__global__ void k_main(const unsigned short* __restrict__ xhi, const unsigned short* __restrict__ xlo,
                       const unsigned short* __restrict__ ehi, const unsigned short* __restrict__ elo,
                       const float* __restrict__ x2, const float* __restrict__ e2,
                       float* __restrict__ dist, unsigned long long* __restrict__ keys) {
    __shared__ unsigned short lds[2][4][128][32];   // dbuf x {Ahi,Alo,Bhi,Blo} x 8KB
    const int tid = threadIdx.x;
    const int l   = tid & 63;
    const int wid = tid >> 6;
    const int wm  = wid >> 1, wn = wid & 1;

    // T1: XCD swizzle (FETCH 265 MB -> 41.6 MB, validated r6).
    const int n   = blockIdx.x;
    const int w_  = (n & 7) * 1024 + (n >> 3);
    const int bx  = w_ & 15;        // code-tile (16)
    const int by  = w_ >> 4;        // token-tile (512)
    const int t0  = by * 128;
    const int c0  = bx * 128;

    const unsigned short* gsrc = (wid == 0) ? xhi : (wid == 1) ? xlo : (wid == 2) ? ehi : elo;
    const int r0 = (wid < 2) ? t0 : c0;

    // chunk pre-swizzle: lane l stages LDS slot (l&3) of row (l>>2)+16i; data
    // landing there is global chunk (l&3)^((l>>3)&3)  (validated r5-r10).
    const int swc = ((l & 3) ^ ((l >> 3) & 3)) * 8;
    const unsigned short* gstage = gsrc + (size_t)(r0 + (l >> 2)) * DIM + swc;

    f32x4 acc[4][4];
    #pragma unroll
    for (int i = 0; i < 4; ++i)
        #pragma unroll
        for (int j = 0; j < 4; ++j) acc[i][j] = (f32x4){0.f, 0.f, 0.f, 0.f};

    const int kg = l >> 4;     // k-group 0..3
    const int lr = l & 15;
    const int ks = (kg ^ ((lr >> 1) & 3)) * 8;   // swizzled slot (shorts) for reads

    // prologue: stage K-step 0 into buf 0
    {
        unsigned short* lb = &lds[0][wid][0][0];
        #pragma unroll
        for (int i = 0; i < 8; ++i)
            async_copy16(gstage + (size_t)i * 16 * DIM, lb + i * 512);
    }
    __syncthreads();

    for (int step = 0; step < 8; ++step) {
        const int cur = step & 1;
        if (step < 7) {   // issue next-step staging first (overlaps ds_read+MFMA)
            const unsigned short* g = gstage + (size_t)(step + 1) * 32;
            unsigned short* lb = &lds[cur ^ 1][wid][0][0];
            #pragma unroll
            for (int i = 0; i < 8; ++i)
                async_copy16(g + (size_t)i * 16 * DIM, lb + i * 512);
        }

        bf16x8 ah[4], al[4], bh[4], bl[4];
        #pragma unroll
        for (int f = 0; f < 4; ++f) {
            ah[f] = *(const bf16x8*)&lds[cur][0][wm * 64 + f * 16 + lr][ks];
            al[f] = *(const bf16x8*)&lds[cur][1][wm * 64 + f * 16 + lr][ks];
            bh[f] = *(const bf16x8*)&lds[cur][2][wn * 64 + f * 16 + lr][ks];
            bl[f] = *(const bf16x8*)&lds[cur][3][wn * 64 + f * 16 + lr][ks];
        }
        __builtin_amdgcn_s_setprio(1);
        #pragma unroll
        for (int mf = 0; mf < 4; ++mf)
            #pragma unroll
            for (int nf = 0; nf < 4; ++nf)
                acc[mf][nf] = MFMA(al[mf], bh[nf], acc[mf][nf]);   // xl*eh
        #pragma unroll
        for (int mf = 0; mf < 4; ++mf)
            #pragma unroll
            for (int nf = 0; nf < 4; ++nf)
                acc[mf][nf] = MFMA(ah[mf], bl[nf], acc[mf][nf]);   // xh*el
        #pragma unroll
        for (int mf = 0; mf < 4; ++mf)
            #pragma unroll
            for (int nf = 0; nf < 4; ++nf)
                acc[mf][nf] = MFMA(ah[mf], bh[nf], acc[mf][nf]);   // xh*eh
        __builtin_amdgcn_s_setprio(0);
        __syncthreads();   // drains vmcnt + barrier; also fences LDS reuse below
    }

    // -------- epilogue: LDS transpose -> full-line dwordx4 dist stores -------
    // Per-wave private slice: 64 rows x 40 floats (stride 40 = 160B, 16B-
    // aligned b128 reads, bank shift 8/row -> 2-way max on reads).
    float* FL = (float*)(&lds[0][0][0][0]) + wid * 2560;   // 10240 B per wave

    const int rl = l >> 3;        // row sub-index 0..7
    const int q  = l & 7;         // 4-col chunk 0..7

    float bs[8];
    int   bc[8];
    #pragma unroll
    for (int c = 0; c < 8; ++c) { bs[c] = FLT_MAX; bc[c] = 0; }

    #pragma unroll
    for (int h = 0; h < 2; ++h) {
        if (h == 1) {
            asm volatile("s_waitcnt lgkmcnt(0)" ::: "memory");  // half-0 reads done
            __builtin_amdgcn_sched_barrier(0);
        }
        // scatter this half's acc (cols 32h..32h+31) into FL
        #pragma unroll
        for (int mf = 0; mf < 4; ++mf)
            #pragma unroll
            for (int reg = 0; reg < 4; ++reg)
                #pragma unroll
                for (int n2 = 0; n2 < 2; ++n2) {
                    int row = mf * 16 + kg * 4 + reg;
                    FL[row * 40 + n2 * 16 + lr] = acc[mf][2 * h + n2][reg];
                }
        asm volatile("s_waitcnt lgkmcnt(0)" ::: "memory");      // writes visible
        __builtin_amdgcn_sched_barrier(0);
        // gather transposed: lane holds 4 CONSECUTIVE cols of one row
        #pragma unroll
        for (int c = 0; c < 8; ++c) {
            int row = 8 * c + rl;
            f32x4 xy = *(const f32x4*)&FL[row * 40 + q * 4];
            int t  = t0 + wm * 64 + row;
            int gc = c0 + wn * 64 + 32 * h + q * 4;
            float tx2 = x2[t];
            f32x4 e24 = *(const f32x4*)&e2[gc];
            f32x4 d;
            #pragma unroll
            for (int j = 0; j < 4; ++j) {
                float sq = fmaxf(tx2 + e24[j] - 2.0f * xy[j], 0.0f);
                d[j] = -sqrtf(sq);
                if (sq < bs[c]) { bs[c] = sq; bc[c] = gc + j; }   // ascending cols: first wins
            }
            // 8 consecutive lanes cover one row: 128B full-line aligned segment
            __builtin_nontemporal_store(d, (f32x4*)(dist + (size_t)t * CODES + gc));
        }
    }

    // row-argmin: reduce across the 8 lanes of each row group, then atomicMin
    #pragma unroll
    for (int c = 0; c < 8; ++c) {
        float s = bs[c];
        int   b = bc[c];
        #pragma unroll
        for (int m = 1; m <= 4; m <<= 1) {
            float os = __shfl_xor(s, m);
            int   ob = __shfl_xor(b, m);
            if (os < s || (os == s && ob < b)) { s = os; b = ob; }
        }
        if ((l & 7) == 0) {
            int t = t0 + wm * 64 + 8 * c + rl;
            unsigned long long key = ((unsigned long long)__float_as_uint(s) << 32) | (unsigned)b;
            atomicMin(keys + t, key);
        }
    }
}

// -------- quantize gather + ind write + count: one wave per TWO tokens -------
__global__ void k_qcount(const float* __restrict__ embed, const unsigned long long* __restrict__ keys,
                         float* __restrict__ q, float* __restrict__ ind_f, int* __restrict__ cnt) {
    int gid  = blockIdx.x * blockDim.x + threadIdx.x;
    int wv   = gid >> 6;
    int lane = threadIdx.x & 63;
    int w0 = wv * 2;
    if (w0 >= N_TOK) return;
    int c0 = (int)(keys[w0] & 0xFFFFFFFFULL);
    int c1 = (int)(keys[w0 + 1] & 0xFFFFFFFFULL);
    f32x4 e0 = reinterpret_cast<const f32x4*>(embed + (size_t)c0 * DIM)[lane];
    f32x4 e1 = reinterpret_cast<const f32x4*>(embed + (size_t)c1 * DIM)[lane];
    __builtin_nontemporal_store(e0, reinterpret_cast<f32x4*>(q + (size_t)w0 * DIM) + lane);
    __builtin_nontemporal_store(e1, reinterpret_cast<f32x4*>(q + (size_t)(w0 + 1) * DIM) + lane);
    if (lane == 0) {
        ind_f[w0] = (float)c0;
        ind_f[w0 + 1] = (float)c1;
        atomicAdd(cnt + c0, 1);
        atomicAdd(cnt + c1, 1);
    }
}

// ---------------- scan: offsets + new_cluster_size + smoothed (fused fin1) ---
__global__ void k_scan(const int* __restrict__ cnt, const float* __restrict__ cs,
                       int* __restrict__ offsets, float* __restrict__ out_ncs,
                       float* __restrict__ smoothed) {
    __shared__ int red[256];
    __shared__ float fred[256];
    __shared__ float s_total;
    int t = threadIdx.x;
    int c8[8];
    int own = 0;
    float ncs8[8];
    float fpart = 0.f;
    #pragma unroll
    for (int r = 0; r < 8; ++r) {
        int c = t * 8 + r;
        int v = cnt[c];
        c8[r] = v;
        own += v;
        float nn = cs[c] * DECAY + (float)v * (1.0f - DECAY);
        out_ncs[c] = nn;
        ncs8[r] = nn;
        fpart += nn;
    }
    red[t] = own;
    fred[t] = fpart;
    __syncthreads();
    for (int d = 1; d < 256; d <<= 1) {
        int v = (t >= d) ? red[t - d] : 0;
        __syncthreads();
        red[t] += v;
        __syncthreads();
    }
    for (int s = 128; s >= 1; s >>= 1) {
        if (t < s) fred[t] += fred[t + s];
        __syncthreads();
    }
    if (t == 0) s_total = fred[0];
    __syncthreads();
    int base = red[t] - own;
    float total = s_total;
    float denom = total + (float)CODES * EPSV;
    #pragma unroll
    for (int r = 0; r < 8; ++r) {
        int c = t * 8 + r;
        offsets[c] = base;
        base += c8[r];
        smoothed[c] = (ncs8[r] + EPSV) / denom * total;
    }
}

// ---------------- scatter token ids into per-code buckets --------------------
__global__ void k_scatter(const unsigned long long* __restrict__ keys,
                          const int* __restrict__ offsets, int* __restrict__ cursor,
                          int* __restrict__ list) {
    int t = blockIdx.x * blockDim.x + threadIdx.x;
    if (t >= N_TOK) return;
    int c = (int)(keys[t] & 0xFFFFFFFFULL);
    int pos = atomicAdd(cursor + c, 1);
    list[offsets[c] + pos] = t;
}

// ---------------- per-code sum of x rows + fused fin2 ------------------------
__global__ void k_esum(const float* __restrict__ x, const int* __restrict__ cnt,
                       const int* __restrict__ offsets, const int* __restrict__ list,
                       const float* __restrict__ ea, const float* __restrict__ smoothed,
                       float* __restrict__ out_nea, float* __restrict__ out_nemb) {
    __shared__ f32x4 part[8][64];
    int c    = blockIdx.x;
    int tid  = threadIdx.x;
    int w    = tid >> 6;
    int lane = tid & 63;
    int n    = cnt[c];
    int off  = offsets[c];
    f32x4 s = (f32x4){0.f, 0.f, 0.f, 0.f};
    for (int i = w; i < n; i += 8) {
        int t = list[off + i];
        s += reinterpret_cast<const f32x4*>(x + (size_t)t * DIM)[lane];
    }
    part[w][lane] = s;
    __syncthreads();
    if (w == 0) {
        f32x4 tot = part[0][lane];
        #pragma unroll
        for (int p = 1; p < 8; ++p) tot += part[p][lane];
        size_t idx = (size_t)c * DIM + lane * 4;
        f32x4 ea4 = *reinterpret_cast<const f32x4*>(ea + idx);
        f32x4 nea;
        float inv = 1.0f / smoothed[c];
        #pragma unroll
        for (int j = 0; j < 4; ++j) nea[j] = ea4[j] * DECAY + tot[j] * (1.0f - DECAY);
        *reinterpret_cast<f32x4*>(out_nea + idx) = nea;
        f32x4 nemb;
        #pragma unroll
        for (int j = 0; j < 4; ++j) nemb[j] = nea[j] * inv;
        *reinterpret_cast<f32x4*>(out_nemb + idx) = nemb;
    }
}

extern "C" void kernel_launch(void* const* d_in, const int* in_sizes, int n_in,
                              void* d_out, int out_size, void* d_ws, size_t ws_size,
                              hipStream_t stream) {
    const float* x     = (const float*)d_in[0];
    const float* embed = (const float*)d_in[1];
    const float* eavg  = (const float*)d_in[2];
    const float* csz   = (const float*)d_in[3];
    float* out = (float*)d_out;
    char*  wsb = (char*)d_ws;

    unsigned long long* keys = (unsigned long long*)(wsb + WSB_KEYS);
    int*            cnt  = (int*)(wsb + WSB_CNT);     // cnt+cur contiguous 16KB
    int*            cur  = (int*)(wsb + WSB_CUR);
    int*            off  = (int*)(wsb + WSB_OFF);
    int*            list = (int*)(wsb + WSB_LIST);
    unsigned short* ehi  = (unsigned short*)(wsb + WSB_EHI);
    unsigned short* elo  = (unsigned short*)(wsb + WSB_ELO);
    float*          x2   = (float*)(wsb + WSB_X2);
    float*          e2   = (float*)(wsb + WSB_E2);
    float*          smoo = (float*)(wsb + WSB_SMOO);

    // x hi/lo staged in the quantize output region (same byte size); k_qcount
    // overwrites it AFTER k_main has consumed it (stream-ordered).
    unsigned short* xhi = (unsigned short*)(out + OUT_Q);
    unsigned short* xlo = xhi + (size_t)N_TOK * DIM;

    k_prep<<<(N_TOK + CODES) * 32 / 256, 256, 0, stream>>>(
        x, embed, xhi, xlo, ehi, elo, x2, e2, keys, cnt);

    k_main<<<(CODES / 128) * (N_TOK / 128), 256, 0, stream>>>(
        xhi, xlo, ehi, elo, x2, e2, out + OUT_DIST, keys);

    k_qcount<<<N_TOK * 32 / 256, 256, 0, stream>>>(embed, keys, out + OUT_Q,
                                                   out + OUT_IND, cnt);
    k_scan<<<1, 256, 0, stream>>>(cnt, csz, off, out + OUT_NCS, smoo);
    k_scatter<<<N_TOK / 256, 256, 0, stream>>>(keys, off, cur, list);
    k_esum<<<CODES, 512, 0, stream>>>(x, cnt, off, list, eavg, smoo,
                                      out + OUT_NEA, out + OUT_NEMB);
}

// Round 13
// 556.886 us; speedup vs baseline: 1.2906x; 1.0119x over previous
//
#include <hip/hip_runtime.h>
#include <float.h>
#include <stdint.h>

// Problem constants (h=1, b=32, n=2048, d=256, c=2048)
#define N_TOK 65536
#define DIM   256
#define CODES 2048
#define DECAY 0.8f
#define EPSV  1e-5f

// Output offsets (floats) in d_out, concatenated in reference return order
#define OUT_Q    ((size_t)0)            // quantize: 16777216
#define OUT_IND  ((size_t)16777216)     // embed_ind: 65536 (written as float)
#define OUT_DIST ((size_t)16842752)     // dist: 134217728
#define OUT_NEMB ((size_t)151060480)    // new_embed: 524288
#define OUT_NCS  ((size_t)151584768)    // new_cluster_size: 2048
#define OUT_NEA  ((size_t)151586816)    // new_embed_avg: 524288

// Workspace layout (bytes)
#define WSB_KEYS ((size_t)0)         // u64[65536] = 524288
#define WSB_CNT  ((size_t)524288)    // int[2048] = 8192   (zeroed in k_prep)
#define WSB_CUR  ((size_t)532480)    // int[2048] = 8192   (zeroed in k_prep)
#define WSB_OFF  ((size_t)540672)    // int[2048] = 8192
#define WSB_LIST ((size_t)548864)    // int[65536] = 262144
#define WSB_EHI  ((size_t)811008)    // ushort[524288] = 1048576
#define WSB_ELO  ((size_t)1859584)   // ushort[524288] = 1048576
#define WSB_X2   ((size_t)2908160)   // f32[65536] = 262144
#define WSB_E2   ((size_t)3170304)   // f32[2048] = 8192
#define WSB_SMOO ((size_t)3178496)   // f32[2048] = 8192

typedef __attribute__((ext_vector_type(8))) short bf16x8;
typedef __attribute__((ext_vector_type(4))) float f32x4;

#define MFMA(a, b, c) __builtin_amdgcn_mfma_f32_16x16x32_bf16(a, b, c, 0, 0, 0)

typedef const unsigned int __attribute__((address_space(1)))* as1_u32p;
typedef unsigned int __attribute__((address_space(3)))* as3_u32p;

__device__ __forceinline__ void async_copy16(const void* g, void* l) {
    __builtin_amdgcn_global_load_lds((as1_u32p)g, (as3_u32p)l, 16, 0, 0);
}

__device__ __forceinline__ unsigned short f2bf(float f) {
    unsigned u = __float_as_uint(f);
    unsigned r = (u + 0x7FFFu + ((u >> 16) & 1u)) >> 16;   // RN-even
    return (unsigned short)r;
}
__device__ __forceinline__ float bf2f(unsigned short s) {
    return __uint_as_float(((unsigned)s) << 16);
}

// ------- prep: split x AND embed to bf16 hi/lo + row |.|^2 + init keys/cnt ---
// one wave per TWO rows (2 independent load/convert/store chains for ILP).
__global__ void k_prep(const float* __restrict__ x, const float* __restrict__ embed,
                       unsigned short* __restrict__ xhi, unsigned short* __restrict__ xlo,
                       unsigned short* __restrict__ ehi, unsigned short* __restrict__ elo,
                       float* __restrict__ x2, float* __restrict__ e2,
                       unsigned long long* __restrict__ keys, int* __restrict__ cntcur) {
    int gid = blockIdx.x * blockDim.x + threadIdx.x;
    if (gid < 4096) cntcur[gid] = 0;                 // cnt + cursor zero
    int wv = gid >> 6;
    int l  = gid & 63;
    #pragma unroll
    for (int half = 0; half < 2; ++half) {
        int r = wv * 2 + half;
        const float* src;
        unsigned short *hi, *lo;
        float* sq;
        int rr;
        if (r < N_TOK) {
            src = x; hi = xhi; lo = xlo; sq = x2; rr = r;
            if (l == 0) keys[r] = 0xFFFFFFFFFFFFFFFFULL;  // argmin key = +inf
        } else {
            src = embed; hi = ehi; lo = elo; sq = e2; rr = r - N_TOK;
        }
        float4 v = reinterpret_cast<const float4*>(src + (size_t)rr * DIM)[l];
        ushort4 h, w;
        h.x = f2bf(v.x); h.y = f2bf(v.y); h.z = f2bf(v.z); h.w = f2bf(v.w);
        w.x = f2bf(v.x - bf2f(h.x));
        w.y = f2bf(v.y - bf2f(h.y));
        w.z = f2bf(v.z - bf2f(h.z));
        w.w = f2bf(v.w - bf2f(h.w));
        reinterpret_cast<ushort4*>(hi + (size_t)rr * DIM)[l] = h;
        reinterpret_cast<ushort4*>(lo + (size_t)rr * DIM)[l] = w;
        float s = v.x * v.x + v.y * v.y + v.z * v.z + v.w * v.w;
        #pragma unroll
        for (int m = 32; m >= 1; m >>= 1) s += __shfl_xor(s, m);
        if (l == 0) sq[rr] = s;
    }
}

// ---------------- main: 3-pass split-bf16 MFMA GEMM + dist + argmin ----------
// K-loop = r7/r12 structure (dbuf + __syncthreads, chunk swizzle, XCD swizzle,
// 3-pass) with: (a) ds_reads issued BEFORE next-step staging (MFMAs start
// earlier), (b) epilogue x2/e2 PREFETCHED into regs before the K-loop (their
// L2 latency hides under ~7400 cyc of MFMA instead of sitting on the epilogue
// critical path), (c) fully unrolled step loop. Epilogue = r12 LDS transpose
// -> 128B full-line dwordx4 NT stores (validated: 702 -> 563 total).
__launch_bounds__(256)
__global__ void k_main(const unsigned short* __restrict__ xhi, const unsigned short* __restrict__ xlo,
                       const unsigned short* __restrict__ ehi, const unsigned short* __restrict__ elo,
                       const float* __restrict__ x2, const float* __restrict__ e2,
                       float* __restrict__ dist, unsigned long long* __restrict__ keys) {
    __shared__ unsigned short lds[2][4][128][32];   // dbuf x {Ahi,Alo,Bhi,Blo} x 8KB
    const int tid = threadIdx.x;
    const int l   = tid & 63;
    const int wid = tid >> 6;
    const int wm  = wid >> 1, wn = wid & 1;

    // T1: XCD swizzle (FETCH 265 MB -> 41.6 MB, validated r6).
    const int n   = blockIdx.x;
    const int w_  = (n & 7) * 1024 + (n >> 3);
    const int bx  = w_ & 15;        // code-tile (16)
    const int by  = w_ >> 4;        // token-tile (512)
    const int t0  = by * 128;
    const int c0  = bx * 128;

    const unsigned short* gsrc = (wid == 0) ? xhi : (wid == 1) ? xlo : (wid == 2) ? ehi : elo;
    const int r0 = (wid < 2) ? t0 : c0;

    // chunk pre-swizzle: lane l stages LDS slot (l&3) of row (l>>2)+16i; data
    // landing there is global chunk (l&3)^((l>>3)&3)  (validated r5-r12).
    const int swc = ((l & 3) ^ ((l >> 3) & 3)) * 8;
    const unsigned short* gstage = gsrc + (size_t)(r0 + (l >> 2)) * DIM + swc;

    f32x4 acc[4][4];
    #pragma unroll
    for (int i = 0; i < 4; ++i)
        #pragma unroll
        for (int j = 0; j < 4; ++j) acc[i][j] = (f32x4){0.f, 0.f, 0.f, 0.f};

    const int kg = l >> 4;     // k-group 0..3
    const int lr = l & 15;
    const int ks = (kg ^ ((lr >> 1) & 3)) * 8;   // swizzled slot (shorts) for reads

    // epilogue operand prefetch (consumed after the K-loop; latency hidden
    // under the MFMA stream). rl/q = epilogue lane mapping.
    const int rl = l >> 3;        // row sub-index 0..7
    const int q  = l & 7;         // 4-col chunk 0..7
    float tx2p[8];
    #pragma unroll
    for (int c = 0; c < 8; ++c) tx2p[c] = x2[t0 + wm * 64 + 8 * c + rl];
    f32x4 e2p[2];
    #pragma unroll
    for (int h = 0; h < 2; ++h)
        e2p[h] = *reinterpret_cast<const f32x4*>(&e2[c0 + wn * 64 + 32 * h + q * 4]);

    // prologue: stage K-step 0 into buf 0
    {
        unsigned short* lb = &lds[0][wid][0][0];
        #pragma unroll
        for (int i = 0; i < 8; ++i)
            async_copy16(gstage + (size_t)i * 16 * DIM, lb + i * 512);
    }
    __syncthreads();

    #pragma unroll
    for (int step = 0; step < 8; ++step) {
        const int cur = step & 1;

        // ds_reads FIRST: MFMAs depend on these, not on the staging below
        bf16x8 ah[4], al[4], bh[4], bl[4];
        #pragma unroll
        for (int f = 0; f < 4; ++f) {
            ah[f] = *(const bf16x8*)&lds[cur][0][wm * 64 + f * 16 + lr][ks];
            al[f] = *(const bf16x8*)&lds[cur][1][wm * 64 + f * 16 + lr][ks];
            bh[f] = *(const bf16x8*)&lds[cur][2][wn * 64 + f * 16 + lr][ks];
            bl[f] = *(const bf16x8*)&lds[cur][3][wn * 64 + f * 16 + lr][ks];
        }
        if (step < 7) {   // issue next-step staging (needed only at the barrier)
            const unsigned short* g = gstage + (size_t)(step + 1) * 32;
            unsigned short* lb = &lds[cur ^ 1][wid][0][0];
            #pragma unroll
            for (int i = 0; i < 8; ++i)
                async_copy16(g + (size_t)i * 16 * DIM, lb + i * 512);
        }

        __builtin_amdgcn_s_setprio(1);
        #pragma unroll
        for (int mf = 0; mf < 4; ++mf)
            #pragma unroll
            for (int nf = 0; nf < 4; ++nf)
                acc[mf][nf] = MFMA(al[mf], bh[nf], acc[mf][nf]);   // xl*eh
        #pragma unroll
        for (int mf = 0; mf < 4; ++mf)
            #pragma unroll
            for (int nf = 0; nf < 4; ++nf)
                acc[mf][nf] = MFMA(ah[mf], bl[nf], acc[mf][nf]);   // xh*el
        #pragma unroll
        for (int mf = 0; mf < 4; ++mf)
            #pragma unroll
            for (int nf = 0; nf < 4; ++nf)
                acc[mf][nf] = MFMA(ah[mf], bh[nf], acc[mf][nf]);   // xh*eh
        __builtin_amdgcn_s_setprio(0);
        __syncthreads();   // drains vmcnt + barrier; also fences LDS reuse below
    }

    // -------- epilogue: LDS transpose -> full-line dwordx4 dist stores -------
    // Per-wave private slice: 64 rows x 40 floats (stride 40 = 160B, 16B-
    // aligned b128 reads, 2-way bank aliasing max).
    float* FL = (float*)(&lds[0][0][0][0]) + wid * 2560;   // 10240 B per wave

    float bs[8];
    int   bc[8];
    #pragma unroll
    for (int c = 0; c < 8; ++c) { bs[c] = FLT_MAX; bc[c] = 0; }

    #pragma unroll
    for (int h = 0; h < 2; ++h) {
        if (h == 1) {
            asm volatile("s_waitcnt lgkmcnt(0)" ::: "memory");  // half-0 reads done
            __builtin_amdgcn_sched_barrier(0);
        }
        // scatter this half's acc (cols 32h..32h+31) into FL
        #pragma unroll
        for (int mf = 0; mf < 4; ++mf)
            #pragma unroll
            for (int reg = 0; reg < 4; ++reg)
                #pragma unroll
                for (int n2 = 0; n2 < 2; ++n2) {
                    int row = mf * 16 + kg * 4 + reg;
                    FL[row * 40 + n2 * 16 + lr] = acc[mf][2 * h + n2][reg];
                }
        asm volatile("s_waitcnt lgkmcnt(0)" ::: "memory");      // writes visible
        __builtin_amdgcn_sched_barrier(0);
        // gather transposed: lane holds 4 CONSECUTIVE cols of one row
        #pragma unroll
        for (int c = 0; c < 8; ++c) {
            int row = 8 * c + rl;
            f32x4 xy = *(const f32x4*)&FL[row * 40 + q * 4];
            int t  = t0 + wm * 64 + row;
            int gc = c0 + wn * 64 + 32 * h + q * 4;
            f32x4 d;
            #pragma unroll
            for (int j = 0; j < 4; ++j) {
                float sq = fmaxf(tx2p[c] + e2p[h][j] - 2.0f * xy[j], 0.0f);
                d[j] = -sqrtf(sq);
                if (sq < bs[c]) { bs[c] = sq; bc[c] = gc + j; }   // ascending cols: first wins
            }
            // 8 consecutive lanes cover one row: 128B full-line aligned segment
            __builtin_nontemporal_store(d, (f32x4*)(dist + (size_t)t * CODES + gc));
        }
    }

    // row-argmin: reduce across the 8 lanes of each row group, then atomicMin
    #pragma unroll
    for (int c = 0; c < 8; ++c) {
        float s = bs[c];
        int   b = bc[c];
        #pragma unroll
        for (int m = 1; m <= 4; m <<= 1) {
            float os = __shfl_xor(s, m);
            int   ob = __shfl_xor(b, m);
            if (os < s || (os == s && ob < b)) { s = os; b = ob; }
        }
        if ((l & 7) == 0) {
            int t = t0 + wm * 64 + 8 * c + rl;
            unsigned long long key = ((unsigned long long)__float_as_uint(s) << 32) | (unsigned)b;
            atomicMin(keys + t, key);
        }
    }
}

// -------- quantize gather + ind write + count: one wave per TWO tokens -------
__global__ void k_qcount(const float* __restrict__ embed, const unsigned long long* __restrict__ keys,
                         float* __restrict__ q, float* __restrict__ ind_f, int* __restrict__ cnt) {
    int gid  = blockIdx.x * blockDim.x + threadIdx.x;
    int wv   = gid >> 6;
    int lane = threadIdx.x & 63;
    int w0 = wv * 2;
    if (w0 >= N_TOK) return;
    int c0 = (int)(keys[w0] & 0xFFFFFFFFULL);
    int c1 = (int)(keys[w0 + 1] & 0xFFFFFFFFULL);
    f32x4 e0 = reinterpret_cast<const f32x4*>(embed + (size_t)c0 * DIM)[lane];
    f32x4 e1 = reinterpret_cast<const f32x4*>(embed + (size_t)c1 * DIM)[lane];
    __builtin_nontemporal_store(e0, reinterpret_cast<f32x4*>(q + (size_t)w0 * DIM) + lane);
    __builtin_nontemporal_store(e1, reinterpret_cast<f32x4*>(q + (size_t)(w0 + 1) * DIM) + lane);
    if (lane == 0) {
        ind_f[w0] = (float)c0;
        ind_f[w0 + 1] = (float)c1;
        atomicAdd(cnt + c0, 1);
        atomicAdd(cnt + c1, 1);
    }
}

// ---------------- scan: offsets + new_cluster_size + smoothed (fused fin1) ---
__global__ void k_scan(const int* __restrict__ cnt, const float* __restrict__ cs,
                       int* __restrict__ offsets, float* __restrict__ out_ncs,
                       float* __restrict__ smoothed) {
    __shared__ int red[256];
    __shared__ float fred[256];
    __shared__ float s_total;
    int t = threadIdx.x;
    int c8[8];
    int own = 0;
    float ncs8[8];
    float fpart = 0.f;
    #pragma unroll
    for (int r = 0; r < 8; ++r) {
        int c = t * 8 + r;
        int v = cnt[c];
        c8[r] = v;
        own += v;
        float nn = cs[c] * DECAY + (float)v * (1.0f - DECAY);
        out_ncs[c] = nn;
        ncs8[r] = nn;
        fpart += nn;
    }
    red[t] = own;
    fred[t] = fpart;
    __syncthreads();
    for (int d = 1; d < 256; d <<= 1) {
        int v = (t >= d) ? red[t - d] : 0;
        __syncthreads();
        red[t] += v;
        __syncthreads();
    }
    for (int s = 128; s >= 1; s >>= 1) {
        if (t < s) fred[t] += fred[t + s];
        __syncthreads();
    }
    if (t == 0) s_total = fred[0];
    __syncthreads();
    int base = red[t] - own;
    float total = s_total;
    float denom = total + (float)CODES * EPSV;
    #pragma unroll
    for (int r = 0; r < 8; ++r) {
        int c = t * 8 + r;
        offsets[c] = base;
        base += c8[r];
        smoothed[c] = (ncs8[r] + EPSV) / denom * total;
    }
}

// ---------------- scatter token ids into per-code buckets --------------------
__global__ void k_scatter(const unsigned long long* __restrict__ keys,
                          const int* __restrict__ offsets, int* __restrict__ cursor,
                          int* __restrict__ list) {
    int t = blockIdx.x * blockDim.x + threadIdx.x;
    if (t >= N_TOK) return;
    int c = (int)(keys[t] & 0xFFFFFFFFULL);
    int pos = atomicAdd(cursor + c, 1);
    list[offsets[c] + pos] = t;
}

// ---------------- per-code sum of x rows + fused fin2 ------------------------
__global__ void k_esum(const float* __restrict__ x, const int* __restrict__ cnt,
                       const int* __restrict__ offsets, const int* __restrict__ list,
                       const float* __restrict__ ea, const float* __restrict__ smoothed,
                       float* __restrict__ out_nea, float* __restrict__ out_nemb) {
    __shared__ f32x4 part[8][64];
    int c    = blockIdx.x;
    int tid  = threadIdx.x;
    int w    = tid >> 6;
    int lane = tid & 63;
    int n    = cnt[c];
    int off  = offsets[c];
    f32x4 s = (f32x4){0.f, 0.f, 0.f, 0.f};
    for (int i = w; i < n; i += 8) {
        int t = list[off + i];
        s += reinterpret_cast<const f32x4*>(x + (size_t)t * DIM)[lane];
    }
    part[w][lane] = s;
    __syncthreads();
    if (w == 0) {
        f32x4 tot = part[0][lane];
        #pragma unroll
        for (int p = 1; p < 8; ++p) tot += part[p][lane];
        size_t idx = (size_t)c * DIM + lane * 4;
        f32x4 ea4 = *reinterpret_cast<const f32x4*>(ea + idx);
        f32x4 nea;
        float inv = 1.0f / smoothed[c];
        #pragma unroll
        for (int j = 0; j < 4; ++j) nea[j] = ea4[j] * DECAY + tot[j] * (1.0f - DECAY);
        *reinterpret_cast<f32x4*>(out_nea + idx) = nea;
        f32x4 nemb;
        #pragma unroll
        for (int j = 0; j < 4; ++j) nemb[j] = nea[j] * inv;
        *reinterpret_cast<f32x4*>(out_nemb + idx) = nemb;
    }
}

extern "C" void kernel_launch(void* const* d_in, const int* in_sizes, int n_in,
                              void* d_out, int out_size, void* d_ws, size_t ws_size,
                              hipStream_t stream) {
    const float* x     = (const float*)d_in[0];
    const float* embed = (const float*)d_in[1];
    const float* eavg  = (const float*)d_in[2];
    const float* csz   = (const float*)d_in[3];
    float* out = (float*)d_out;
    char*  wsb = (char*)d_ws;

    unsigned long long* keys = (unsigned long long*)(wsb + WSB_KEYS);
    int*            cnt  = (int*)(wsb + WSB_CNT);     // cnt+cur contiguous 16KB
    int*            cur  = (int*)(wsb + WSB_CUR);
    int*            off  = (int*)(wsb + WSB_OFF);
    int*            list = (int*)(wsb + WSB_LIST);
    unsigned short* ehi  = (unsigned short*)(wsb + WSB_EHI);
    unsigned short* elo  = (unsigned short*)(wsb + WSB_ELO);
    float*          x2   = (float*)(wsb + WSB_X2);
    float*          e2   = (float*)(wsb + WSB_E2);
    float*          smoo = (float*)(wsb + WSB_SMOO);

    // x hi/lo staged in the quantize output region (same byte size); k_qcount
    // overwrites it AFTER k_main has consumed it (stream-ordered).
    unsigned short* xhi = (unsigned short*)(out + OUT_Q);
    unsigned short* xlo = xhi + (size_t)N_TOK * DIM;

    k_prep<<<(N_TOK + CODES) * 32 / 256, 256, 0, stream>>>(
        x, embed, xhi, xlo, ehi, elo, x2, e2, keys, cnt);

    k_main<<<(CODES / 128) * (N_TOK / 128), 256, 0, stream>>>(
        xhi, xlo, ehi, elo, x2, e2, out + OUT_DIST, keys);

    k_qcount<<<N_TOK * 32 / 256, 256, 0, stream>>>(embed, keys, out + OUT_Q,
                                                   out + OUT_IND, cnt);
    k_scan<<<1, 256, 0, stream>>>(cnt, csz, off, out + OUT_NCS, smoo);
    k_scatter<<<N_TOK / 256, 256, 0, stream>>>(keys, off, cur, list);
    k_esum<<<CODES, 512, 0, stream>>>(x, cnt, off, list, eavg, smoo,
                                      out + OUT_NEA, out + OUT_NEMB);
}

// Round 14
// 486.305 us; speedup vs baseline: 1.4779x; 1.1451x over previous
//
#include <hip/hip_runtime.h>
#include <float.h>
#include <stdint.h>

// Problem constants (h=1, b=32, n=2048, d=256, c=2048)
#define N_TOK 65536
#define DIM   256
#define CODES 2048
#define DECAY 0.8f
#define EPSV  1e-5f

// Output offsets (floats) in d_out, concatenated in reference return order
#define OUT_Q    ((size_t)0)            // quantize: 16777216
#define OUT_IND  ((size_t)16777216)     // embed_ind: 65536 (written as float)
#define OUT_DIST ((size_t)16842752)     // dist: 134217728
#define OUT_NEMB ((size_t)151060480)    // new_embed: 524288
#define OUT_NCS  ((size_t)151584768)    // new_cluster_size: 2048
#define OUT_NEA  ((size_t)151586816)    // new_embed_avg: 524288

// Workspace layout (bytes)
#define WSB_KEYS ((size_t)0)         // u64[65536] = 524288
#define WSB_CNT  ((size_t)524288)    // int[2048] = 8192   (zeroed in k_prep)
#define WSB_CUR  ((size_t)532480)    // int[2048] = 8192   (zeroed in k_prep)
#define WSB_OFF  ((size_t)540672)    // int[2048] = 8192
#define WSB_LIST ((size_t)548864)    // int[65536] = 262144
#define WSB_EHI  ((size_t)811008)    // ushort[524288] = 1048576
#define WSB_ELO  ((size_t)1859584)   // ushort[524288] = 1048576
#define WSB_X2   ((size_t)2908160)   // f32[65536] = 262144
#define WSB_E2   ((size_t)3170304)   // f32[2048] = 8192
#define WSB_SMOO ((size_t)3178496)   // f32[2048] = 8192

typedef __attribute__((ext_vector_type(8))) short bf16x8;
typedef __attribute__((ext_vector_type(4))) float f32x4;

#define MFMA(a, b, c) __builtin_amdgcn_mfma_f32_16x16x32_bf16(a, b, c, 0, 0, 0)

typedef const unsigned int __attribute__((address_space(1)))* as1_u32p;
typedef unsigned int __attribute__((address_space(3)))* as3_u32p;

__device__ __forceinline__ void async_copy16(const void* g, void* l) {
    __builtin_amdgcn_global_load_lds((as1_u32p)g, (as3_u32p)l, 16, 0, 0);
}

__device__ __forceinline__ unsigned short f2bf(float f) {
    unsigned u = __float_as_uint(f);
    unsigned r = (u + 0x7FFFu + ((u >> 16) & 1u)) >> 16;   // RN-even
    return (unsigned short)r;
}
__device__ __forceinline__ float bf2f(unsigned short s) {
    return __uint_as_float(((unsigned)s) << 16);
}

// ------- prep: split x AND embed to bf16 hi/lo + row |.|^2 + init keys/cnt ---
// one wave per TWO rows (2 independent load/convert/store chains for ILP).
__global__ void k_prep(const float* __restrict__ x, const float* __restrict__ embed,
                       unsigned short* __restrict__ xhi, unsigned short* __restrict__ xlo,
                       unsigned short* __restrict__ ehi, unsigned short* __restrict__ elo,
                       float* __restrict__ x2, float* __restrict__ e2,
                       unsigned long long* __restrict__ keys, int* __restrict__ cntcur) {
    int gid = blockIdx.x * blockDim.x + threadIdx.x;
    if (gid < 4096) cntcur[gid] = 0;                 // cnt + cursor zero
    int wv = gid >> 6;
    int l  = gid & 63;
    #pragma unroll
    for (int half = 0; half < 2; ++half) {
        int r = wv * 2 + half;
        const float* src;
        unsigned short *hi, *lo;
        float* sq;
        int rr;
        if (r < N_TOK) {
            src = x; hi = xhi; lo = xlo; sq = x2; rr = r;
            if (l == 0) keys[r] = 0xFFFFFFFFFFFFFFFFULL;  // argmin key = +inf
        } else {
            src = embed; hi = ehi; lo = elo; sq = e2; rr = r - N_TOK;
        }
        float4 v = reinterpret_cast<const float4*>(src + (size_t)rr * DIM)[l];
        ushort4 h, w;
        h.x = f2bf(v.x); h.y = f2bf(v.y); h.z = f2bf(v.z); h.w = f2bf(v.w);
        w.x = f2bf(v.x - bf2f(h.x));
        w.y = f2bf(v.y - bf2f(h.y));
        w.z = f2bf(v.z - bf2f(h.z));
        w.w = f2bf(v.w - bf2f(h.w));
        reinterpret_cast<ushort4*>(hi + (size_t)rr * DIM)[l] = h;
        reinterpret_cast<ushort4*>(lo + (size_t)rr * DIM)[l] = w;
        float s = v.x * v.x + v.y * v.y + v.z * v.z + v.w * v.w;
        #pragma unroll
        for (int m = 32; m >= 1; m >>= 1) s += __shfl_xor(s, m);
        if (l == 0) sq[rr] = s;
    }
}

// ---------------- main: 3-pass split-bf16 MFMA GEMM + dist + argmin ----------
// Frozen r13 structure: dbuf + __syncthreads K-loop, chunk swizzle, XCD
// swizzle, 3-pass, ds_read-before-stage, epilogue operand prefetch, LDS-
// transpose epilogue with 128B full-line dwordx4 NT stores.
__launch_bounds__(256)
__global__ void k_main(const unsigned short* __restrict__ xhi, const unsigned short* __restrict__ xlo,
                       const unsigned short* __restrict__ ehi, const unsigned short* __restrict__ elo,
                       const float* __restrict__ x2, const float* __restrict__ e2,
                       float* __restrict__ dist, unsigned long long* __restrict__ keys) {
    __shared__ unsigned short lds[2][4][128][32];   // dbuf x {Ahi,Alo,Bhi,Blo} x 8KB
    const int tid = threadIdx.x;
    const int l   = tid & 63;
    const int wid = tid >> 6;
    const int wm  = wid >> 1, wn = wid & 1;

    // T1: XCD swizzle (FETCH 265 MB -> 41.6 MB, validated r6).
    const int n   = blockIdx.x;
    const int w_  = (n & 7) * 1024 + (n >> 3);
    const int bx  = w_ & 15;        // code-tile (16)
    const int by  = w_ >> 4;        // token-tile (512)
    const int t0  = by * 128;
    const int c0  = bx * 128;

    const unsigned short* gsrc = (wid == 0) ? xhi : (wid == 1) ? xlo : (wid == 2) ? ehi : elo;
    const int r0 = (wid < 2) ? t0 : c0;

    // chunk pre-swizzle: lane l stages LDS slot (l&3) of row (l>>2)+16i; data
    // landing there is global chunk (l&3)^((l>>3)&3)  (validated r5-r12).
    const int swc = ((l & 3) ^ ((l >> 3) & 3)) * 8;
    const unsigned short* gstage = gsrc + (size_t)(r0 + (l >> 2)) * DIM + swc;

    f32x4 acc[4][4];
    #pragma unroll
    for (int i = 0; i < 4; ++i)
        #pragma unroll
        for (int j = 0; j < 4; ++j) acc[i][j] = (f32x4){0.f, 0.f, 0.f, 0.f};

    const int kg = l >> 4;     // k-group 0..3
    const int lr = l & 15;
    const int ks = (kg ^ ((lr >> 1) & 3)) * 8;   // swizzled slot (shorts) for reads

    // epilogue operand prefetch (latency hidden under the MFMA stream)
    const int rl = l >> 3;        // row sub-index 0..7
    const int q  = l & 7;         // 4-col chunk 0..7
    float tx2p[8];
    #pragma unroll
    for (int c = 0; c < 8; ++c) tx2p[c] = x2[t0 + wm * 64 + 8 * c + rl];
    f32x4 e2p[2];
    #pragma unroll
    for (int h = 0; h < 2; ++h)
        e2p[h] = *reinterpret_cast<const f32x4*>(&e2[c0 + wn * 64 + 32 * h + q * 4]);

    // prologue: stage K-step 0 into buf 0
    {
        unsigned short* lb = &lds[0][wid][0][0];
        #pragma unroll
        for (int i = 0; i < 8; ++i)
            async_copy16(gstage + (size_t)i * 16 * DIM, lb + i * 512);
    }
    __syncthreads();

    #pragma unroll
    for (int step = 0; step < 8; ++step) {
        const int cur = step & 1;

        // ds_reads FIRST: MFMAs depend on these, not on the staging below
        bf16x8 ah[4], al[4], bh[4], bl[4];
        #pragma unroll
        for (int f = 0; f < 4; ++f) {
            ah[f] = *(const bf16x8*)&lds[cur][0][wm * 64 + f * 16 + lr][ks];
            al[f] = *(const bf16x8*)&lds[cur][1][wm * 64 + f * 16 + lr][ks];
            bh[f] = *(const bf16x8*)&lds[cur][2][wn * 64 + f * 16 + lr][ks];
            bl[f] = *(const bf16x8*)&lds[cur][3][wn * 64 + f * 16 + lr][ks];
        }
        if (step < 7) {   // issue next-step staging (needed only at the barrier)
            const unsigned short* g = gstage + (size_t)(step + 1) * 32;
            unsigned short* lb = &lds[cur ^ 1][wid][0][0];
            #pragma unroll
            for (int i = 0; i < 8; ++i)
                async_copy16(g + (size_t)i * 16 * DIM, lb + i * 512);
        }

        __builtin_amdgcn_s_setprio(1);
        #pragma unroll
        for (int mf = 0; mf < 4; ++mf)
            #pragma unroll
            for (int nf = 0; nf < 4; ++nf)
                acc[mf][nf] = MFMA(al[mf], bh[nf], acc[mf][nf]);   // xl*eh
        #pragma unroll
        for (int mf = 0; mf < 4; ++mf)
            #pragma unroll
            for (int nf = 0; nf < 4; ++nf)
                acc[mf][nf] = MFMA(ah[mf], bl[nf], acc[mf][nf]);   // xh*el
        #pragma unroll
        for (int mf = 0; mf < 4; ++mf)
            #pragma unroll
            for (int nf = 0; nf < 4; ++nf)
                acc[mf][nf] = MFMA(ah[mf], bh[nf], acc[mf][nf]);   // xh*eh
        __builtin_amdgcn_s_setprio(0);
        __syncthreads();   // drains vmcnt + barrier; also fences LDS reuse below
    }

    // -------- epilogue: LDS transpose -> full-line dwordx4 dist stores -------
    float* FL = (float*)(&lds[0][0][0][0]) + wid * 2560;   // 10240 B per wave

    float bs[8];
    int   bc[8];
    #pragma unroll
    for (int c = 0; c < 8; ++c) { bs[c] = FLT_MAX; bc[c] = 0; }

    #pragma unroll
    for (int h = 0; h < 2; ++h) {
        if (h == 1) {
            asm volatile("s_waitcnt lgkmcnt(0)" ::: "memory");  // half-0 reads done
            __builtin_amdgcn_sched_barrier(0);
        }
        // scatter this half's acc (cols 32h..32h+31) into FL
        #pragma unroll
        for (int mf = 0; mf < 4; ++mf)
            #pragma unroll
            for (int reg = 0; reg < 4; ++reg)
                #pragma unroll
                for (int n2 = 0; n2 < 2; ++n2) {
                    int row = mf * 16 + kg * 4 + reg;
                    FL[row * 40 + n2 * 16 + lr] = acc[mf][2 * h + n2][reg];
                }
        asm volatile("s_waitcnt lgkmcnt(0)" ::: "memory");      // writes visible
        __builtin_amdgcn_sched_barrier(0);
        // gather transposed: lane holds 4 CONSECUTIVE cols of one row
        #pragma unroll
        for (int c = 0; c < 8; ++c) {
            int row = 8 * c + rl;
            f32x4 xy = *(const f32x4*)&FL[row * 40 + q * 4];
            int t  = t0 + wm * 64 + row;
            int gc = c0 + wn * 64 + 32 * h + q * 4;
            f32x4 d;
            #pragma unroll
            for (int j = 0; j < 4; ++j) {
                float sq = fmaxf(tx2p[c] + e2p[h][j] - 2.0f * xy[j], 0.0f);
                d[j] = -sqrtf(sq);
                if (sq < bs[c]) { bs[c] = sq; bc[c] = gc + j; }   // ascending cols: first wins
            }
            // 8 consecutive lanes cover one row: 128B full-line aligned segment
            __builtin_nontemporal_store(d, (f32x4*)(dist + (size_t)t * CODES + gc));
        }
    }

    // row-argmin: reduce across the 8 lanes of each row group, then atomicMin
    #pragma unroll
    for (int c = 0; c < 8; ++c) {
        float s = bs[c];
        int   b = bc[c];
        #pragma unroll
        for (int m = 1; m <= 4; m <<= 1) {
            float os = __shfl_xor(s, m);
            int   ob = __shfl_xor(b, m);
            if (os < s || (os == s && ob < b)) { s = os; b = ob; }
        }
        if ((l & 7) == 0) {
            int t = t0 + wm * 64 + 8 * c + rl;
            unsigned long long key = ((unsigned long long)__float_as_uint(s) << 32) | (unsigned)b;
            atomicMin(keys + t, key);
        }
    }
}

// -------- quantize gather + ind write + count: one wave per TWO tokens -------
__global__ void k_qcount(const float* __restrict__ embed, const unsigned long long* __restrict__ keys,
                         float* __restrict__ q, float* __restrict__ ind_f, int* __restrict__ cnt) {
    int gid  = blockIdx.x * blockDim.x + threadIdx.x;
    int wv   = gid >> 6;
    int lane = threadIdx.x & 63;
    int w0 = wv * 2;
    if (w0 >= N_TOK) return;
    int c0 = (int)(keys[w0] & 0xFFFFFFFFULL);
    int c1 = (int)(keys[w0 + 1] & 0xFFFFFFFFULL);
    f32x4 e0 = reinterpret_cast<const f32x4*>(embed + (size_t)c0 * DIM)[lane];
    f32x4 e1 = reinterpret_cast<const f32x4*>(embed + (size_t)c1 * DIM)[lane];
    __builtin_nontemporal_store(e0, reinterpret_cast<f32x4*>(q + (size_t)w0 * DIM) + lane);
    __builtin_nontemporal_store(e1, reinterpret_cast<f32x4*>(q + (size_t)(w0 + 1) * DIM) + lane);
    if (lane == 0) {
        ind_f[w0] = (float)c0;
        ind_f[w0 + 1] = (float)c1;
        atomicAdd(cnt + c0, 1);
        atomicAdd(cnt + c1, 1);
    }
}

// ---------------- scan: offsets + new_cluster_size + smoothed (fused fin1) ---
__global__ void k_scan(const int* __restrict__ cnt, const float* __restrict__ cs,
                       int* __restrict__ offsets, float* __restrict__ out_ncs,
                       float* __restrict__ smoothed) {
    __shared__ int red[256];
    __shared__ float fred[256];
    __shared__ float s_total;
    int t = threadIdx.x;
    int c8[8];
    int own = 0;
    float ncs8[8];
    float fpart = 0.f;
    #pragma unroll
    for (int r = 0; r < 8; ++r) {
        int c = t * 8 + r;
        int v = cnt[c];
        c8[r] = v;
        own += v;
        float nn = cs[c] * DECAY + (float)v * (1.0f - DECAY);
        out_ncs[c] = nn;
        ncs8[r] = nn;
        fpart += nn;
    }
    red[t] = own;
    fred[t] = fpart;
    __syncthreads();
    for (int d = 1; d < 256; d <<= 1) {
        int v = (t >= d) ? red[t - d] : 0;
        __syncthreads();
        red[t] += v;
        __syncthreads();
    }
    for (int s = 128; s >= 1; s >>= 1) {
        if (t < s) fred[t] += fred[t + s];
        __syncthreads();
    }
    if (t == 0) s_total = fred[0];
    __syncthreads();
    int base = red[t] - own;
    float total = s_total;
    float denom = total + (float)CODES * EPSV;
    #pragma unroll
    for (int r = 0; r < 8; ++r) {
        int c = t * 8 + r;
        offsets[c] = base;
        base += c8[r];
        smoothed[c] = (ncs8[r] + EPSV) / denom * total;
    }
}

// ---------------- scatter token ids into per-code buckets --------------------
__global__ void k_scatter(const unsigned long long* __restrict__ keys,
                          const int* __restrict__ offsets, int* __restrict__ cursor,
                          int* __restrict__ list) {
    int t = blockIdx.x * blockDim.x + threadIdx.x;
    if (t >= N_TOK) return;
    int c = (int)(keys[t] & 0xFFFFFFFFULL);
    int pos = atomicAdd(cursor + c, 1);
    list[offsets[c] + pos] = t;
}

// ---------------- per-code sum of x rows + fused fin2 ------------------------
// 16 waves/block; each wave processes 4 CONSECUTIVE list entries per iteration
// (4 uniform index loads issue together -> 4 independent row gathers in
// flight), stride 64. Kills the skewed-bucket straggler: the dependent
// {index load -> row gather} chain is amortized 4x and per-wave iteration
// count halved vs the old 8-wave/1-entry loop.
__global__ void k_esum(const float* __restrict__ x, const int* __restrict__ cnt,
                       const int* __restrict__ offsets, const int* __restrict__ list,
                       const float* __restrict__ ea, const float* __restrict__ smoothed,
                       float* __restrict__ out_nea, float* __restrict__ out_nemb) {
    __shared__ f32x4 part[16][64];
    int c    = blockIdx.x;
    int tid  = threadIdx.x;
    int w    = tid >> 6;          // 0..15
    int lane = tid & 63;
    int n    = cnt[c];
    int off  = offsets[c];
    f32x4 s = (f32x4){0.f, 0.f, 0.f, 0.f};
    for (int i = w * 4; i < n; i += 64) {
        #pragma unroll
        for (int j = 0; j < 4; ++j) {
            if (i + j < n) {
                int t = list[off + i + j];
                s += reinterpret_cast<const f32x4*>(x + (size_t)t * DIM)[lane];
            }
        }
    }
    part[w][lane] = s;
    __syncthreads();
    if (w == 0) {
        f32x4 tot = part[0][lane];
        #pragma unroll
        for (int p = 1; p < 16; ++p) tot += part[p][lane];
        size_t idx = (size_t)c * DIM + lane * 4;
        f32x4 ea4 = *reinterpret_cast<const f32x4*>(ea + idx);
        f32x4 nea;
        float inv = 1.0f / smoothed[c];
        #pragma unroll
        for (int j = 0; j < 4; ++j) nea[j] = ea4[j] * DECAY + tot[j] * (1.0f - DECAY);
        *reinterpret_cast<f32x4*>(out_nea + idx) = nea;
        f32x4 nemb;
        #pragma unroll
        for (int j = 0; j < 4; ++j) nemb[j] = nea[j] * inv;
        *reinterpret_cast<f32x4*>(out_nemb + idx) = nemb;
    }
}

extern "C" void kernel_launch(void* const* d_in, const int* in_sizes, int n_in,
                              void* d_out, int out_size, void* d_ws, size_t ws_size,
                              hipStream_t stream) {
    const float* x     = (const float*)d_in[0];
    const float* embed = (const float*)d_in[1];
    const float* eavg  = (const float*)d_in[2];
    const float* csz   = (const float*)d_in[3];
    float* out = (float*)d_out;
    char*  wsb = (char*)d_ws;

    unsigned long long* keys = (unsigned long long*)(wsb + WSB_KEYS);
    int*            cnt  = (int*)(wsb + WSB_CNT);     // cnt+cur contiguous 16KB
    int*            cur  = (int*)(wsb + WSB_CUR);
    int*            off  = (int*)(wsb + WSB_OFF);
    int*            list = (int*)(wsb + WSB_LIST);
    unsigned short* ehi  = (unsigned short*)(wsb + WSB_EHI);
    unsigned short* elo  = (unsigned short*)(wsb + WSB_ELO);
    float*          x2   = (float*)(wsb + WSB_X2);
    float*          e2   = (float*)(wsb + WSB_E2);
    float*          smoo = (float*)(wsb + WSB_SMOO);

    // x hi/lo staged in the quantize output region (same byte size); k_qcount
    // overwrites it AFTER k_main has consumed it (stream-ordered).
    unsigned short* xhi = (unsigned short*)(out + OUT_Q);
    unsigned short* xlo = xhi + (size_t)N_TOK * DIM;

    k_prep<<<(N_TOK + CODES) * 32 / 256, 256, 0, stream>>>(
        x, embed, xhi, xlo, ehi, elo, x2, e2, keys, cnt);

    k_main<<<(CODES / 128) * (N_TOK / 128), 256, 0, stream>>>(
        xhi, xlo, ehi, elo, x2, e2, out + OUT_DIST, keys);

    k_qcount<<<N_TOK * 32 / 256, 256, 0, stream>>>(embed, keys, out + OUT_Q,
                                                   out + OUT_IND, cnt);
    k_scan<<<1, 256, 0, stream>>>(cnt, csz, off, out + OUT_NCS, smoo);
    k_scatter<<<N_TOK / 256, 256, 0, stream>>>(keys, off, cur, list);
    k_esum<<<CODES, 1024, 0, stream>>>(x, cnt, off, list, eavg, smoo,
                                       out + OUT_NEA, out + OUT_NEMB);
}

// Round 15
// 477.002 us; speedup vs baseline: 1.5067x; 1.0195x over previous
//
#include <hip/hip_runtime.h>
#include <float.h>
#include <stdint.h>

// Problem constants (h=1, b=32, n=2048, d=256, c=2048)
#define N_TOK 65536
#define DIM   256
#define CODES 2048
#define DECAY 0.8f
#define EPSV  1e-5f

// Output offsets (floats) in d_out, concatenated in reference return order
#define OUT_Q    ((size_t)0)            // quantize: 16777216
#define OUT_IND  ((size_t)16777216)     // embed_ind: 65536 (written as float)
#define OUT_DIST ((size_t)16842752)     // dist: 134217728
#define OUT_NEMB ((size_t)151060480)    // new_embed: 524288
#define OUT_NCS  ((size_t)151584768)    // new_cluster_size: 2048
#define OUT_NEA  ((size_t)151586816)    // new_embed_avg: 524288

// Workspace layout (bytes)
#define WSB_KEYS ((size_t)0)         // u64[65536] = 524288
#define WSB_CNT  ((size_t)524288)    // int[2048] = 8192   (zeroed in k_prep)
#define WSB_CUR  ((size_t)532480)    // int[2048] = 8192   (zeroed in k_prep)
#define WSB_OFF  ((size_t)540672)    // int[2048] = 8192
#define WSB_LIST ((size_t)548864)    // int[65536] = 262144
#define WSB_EHI  ((size_t)811008)    // ushort[524288] = 1048576
#define WSB_ELO  ((size_t)1859584)   // ushort[524288] = 1048576
#define WSB_X2   ((size_t)2908160)   // f32[65536] = 262144
#define WSB_E2   ((size_t)3170304)   // f32[2048] = 8192
#define WSB_SMOO ((size_t)3178496)   // f32[2048] = 8192

typedef __attribute__((ext_vector_type(8))) short bf16x8;
typedef __attribute__((ext_vector_type(4))) float f32x4;

#define MFMA(a, b, c) __builtin_amdgcn_mfma_f32_16x16x32_bf16(a, b, c, 0, 0, 0)

typedef const unsigned int __attribute__((address_space(1)))* as1_u32p;
typedef unsigned int __attribute__((address_space(3)))* as3_u32p;

__device__ __forceinline__ void async_copy16(const void* g, void* l) {
    __builtin_amdgcn_global_load_lds((as1_u32p)g, (as3_u32p)l, 16, 0, 0);
}

__device__ __forceinline__ unsigned short f2bf(float f) {
    unsigned u = __float_as_uint(f);
    unsigned r = (u + 0x7FFFu + ((u >> 16) & 1u)) >> 16;   // RN-even
    return (unsigned short)r;
}
__device__ __forceinline__ float bf2f(unsigned short s) {
    return __uint_as_float(((unsigned)s) << 16);
}

// ------- prep: split x AND embed to bf16 hi/lo + row |.|^2 + init keys/cnt ---
// one wave per TWO rows (2 independent load/convert/store chains for ILP).
__global__ void k_prep(const float* __restrict__ x, const float* __restrict__ embed,
                       unsigned short* __restrict__ xhi, unsigned short* __restrict__ xlo,
                       unsigned short* __restrict__ ehi, unsigned short* __restrict__ elo,
                       float* __restrict__ x2, float* __restrict__ e2,
                       unsigned long long* __restrict__ keys, int* __restrict__ cntcur) {
    int gid = blockIdx.x * blockDim.x + threadIdx.x;
    if (gid < 4096) cntcur[gid] = 0;                 // cnt + cursor zero
    int wv = gid >> 6;
    int l  = gid & 63;
    #pragma unroll
    for (int half = 0; half < 2; ++half) {
        int r = wv * 2 + half;
        const float* src;
        unsigned short *hi, *lo;
        float* sq;
        int rr;
        if (r < N_TOK) {
            src = x; hi = xhi; lo = xlo; sq = x2; rr = r;
            if (l == 0) keys[r] = 0xFFFFFFFFFFFFFFFFULL;  // argmin key = +inf
        } else {
            src = embed; hi = ehi; lo = elo; sq = e2; rr = r - N_TOK;
        }
        float4 v = reinterpret_cast<const float4*>(src + (size_t)rr * DIM)[l];
        ushort4 h, w;
        h.x = f2bf(v.x); h.y = f2bf(v.y); h.z = f2bf(v.z); h.w = f2bf(v.w);
        w.x = f2bf(v.x - bf2f(h.x));
        w.y = f2bf(v.y - bf2f(h.y));
        w.z = f2bf(v.z - bf2f(h.z));
        w.w = f2bf(v.w - bf2f(h.w));
        reinterpret_cast<ushort4*>(hi + (size_t)rr * DIM)[l] = h;
        reinterpret_cast<ushort4*>(lo + (size_t)rr * DIM)[l] = w;
        float s = v.x * v.x + v.y * v.y + v.z * v.z + v.w * v.w;
        #pragma unroll
        for (int m = 32; m >= 1; m >>= 1) s += __shfl_xor(s, m);
        if (l == 0) sq[rr] = s;
    }
}

// ---------------- main: 3-pass split-bf16 MFMA GEMM + dist + argmin ----------
// r13 structure with the sync scheme changed to COUNTED vmcnt(8) + raw
// barriers, WITHOUT sched_barrier pinning (r6 bundled both; m141 says the
// pinning is the poison). Next-step staging loads stay in flight across the
// barrier instead of draining to 0 every step. Epilogue = r12 LDS transpose
// -> 128B full-line dwordx4 NT stores (validated).
__launch_bounds__(256)
__global__ void k_main(const unsigned short* __restrict__ xhi, const unsigned short* __restrict__ xlo,
                       const unsigned short* __restrict__ ehi, const unsigned short* __restrict__ elo,
                       const float* __restrict__ x2, const float* __restrict__ e2,
                       float* __restrict__ dist, unsigned long long* __restrict__ keys) {
    __shared__ unsigned short lds[2][4][128][32];   // dbuf x {Ahi,Alo,Bhi,Blo} x 8KB
    const int tid = threadIdx.x;
    const int l   = tid & 63;
    const int wid = tid >> 6;
    const int wm  = wid >> 1, wn = wid & 1;

    // T1: XCD swizzle (FETCH 265 MB -> 41.6 MB, validated r6).
    const int n   = blockIdx.x;
    const int w_  = (n & 7) * 1024 + (n >> 3);
    const int bx  = w_ & 15;        // code-tile (16)
    const int by  = w_ >> 4;        // token-tile (512)
    const int t0  = by * 128;
    const int c0  = bx * 128;

    const unsigned short* gsrc = (wid == 0) ? xhi : (wid == 1) ? xlo : (wid == 2) ? ehi : elo;
    const int r0 = (wid < 2) ? t0 : c0;

    // chunk pre-swizzle: lane l stages LDS slot (l&3) of row (l>>2)+16i; data
    // landing there is global chunk (l&3)^((l>>3)&3)  (validated r5-r14).
    const int swc = ((l & 3) ^ ((l >> 3) & 3)) * 8;
    const unsigned short* gstage = gsrc + (size_t)(r0 + (l >> 2)) * DIM + swc;

    f32x4 acc[4][4];
    #pragma unroll
    for (int i = 0; i < 4; ++i)
        #pragma unroll
        for (int j = 0; j < 4; ++j) acc[i][j] = (f32x4){0.f, 0.f, 0.f, 0.f};

    const int kg = l >> 4;     // k-group 0..3
    const int lr = l & 15;
    const int ks = (kg ^ ((lr >> 1) & 3)) * 8;   // swizzled slot (shorts) for reads

    // epilogue operand prefetch (latency hidden under the MFMA stream)
    const int rl = l >> 3;        // row sub-index 0..7
    const int q  = l & 7;         // 4-col chunk 0..7
    float tx2p[8];
    #pragma unroll
    for (int c = 0; c < 8; ++c) tx2p[c] = x2[t0 + wm * 64 + 8 * c + rl];
    f32x4 e2p[2];
    #pragma unroll
    for (int h = 0; h < 2; ++h)
        e2p[h] = *reinterpret_cast<const f32x4*>(&e2[c0 + wn * 64 + 32 * h + q * 4]);

    // prologue: stage K-step 0 into buf 0 (8 loads in flight)
    {
        unsigned short* lb = &lds[0][wid][0][0];
        #pragma unroll
        for (int i = 0; i < 8; ++i)
            async_copy16(gstage + (size_t)i * 16 * DIM, lb + i * 512);
    }

    #pragma unroll
    for (int step = 0; step < 8; ++step) {
        const int cur = step & 1;
        if (step < 7) {
            // issue next-step staging (8 more; 16 outstanding per wave)
            const unsigned short* g = gstage + (size_t)(step + 1) * 32;
            unsigned short* lb = &lds[cur ^ 1][wid][0][0];
            #pragma unroll
            for (int i = 0; i < 8; ++i)
                async_copy16(g + (size_t)i * 16 * DIM, lb + i * 512);
            // wait until only next-step's 8 remain: cur's 8 retired (per-wave FIFO)
            asm volatile("s_waitcnt vmcnt(8)" ::: "memory");
        } else {
            asm volatile("s_waitcnt vmcnt(0)" ::: "memory");
        }
        __builtin_amdgcn_s_barrier();   // all waves' cur tile staged; NO vmcnt0 drain

        bf16x8 ah[4], al[4], bh[4], bl[4];
        #pragma unroll
        for (int f = 0; f < 4; ++f) {
            ah[f] = *(const bf16x8*)&lds[cur][0][wm * 64 + f * 16 + lr][ks];
            al[f] = *(const bf16x8*)&lds[cur][1][wm * 64 + f * 16 + lr][ks];
            bh[f] = *(const bf16x8*)&lds[cur][2][wn * 64 + f * 16 + lr][ks];
            bl[f] = *(const bf16x8*)&lds[cur][3][wn * 64 + f * 16 + lr][ks];
        }
        __builtin_amdgcn_s_setprio(1);
        #pragma unroll
        for (int mf = 0; mf < 4; ++mf)
            #pragma unroll
            for (int nf = 0; nf < 4; ++nf)
                acc[mf][nf] = MFMA(al[mf], bh[nf], acc[mf][nf]);   // xl*eh
        #pragma unroll
        for (int mf = 0; mf < 4; ++mf)
            #pragma unroll
            for (int nf = 0; nf < 4; ++nf)
                acc[mf][nf] = MFMA(ah[mf], bl[nf], acc[mf][nf]);   // xh*el
        #pragma unroll
        for (int mf = 0; mf < 4; ++mf)
            #pragma unroll
            for (int nf = 0; nf < 4; ++nf)
                acc[mf][nf] = MFMA(ah[mf], bh[nf], acc[mf][nf]);   // xh*eh
        __builtin_amdgcn_s_setprio(0);
        __builtin_amdgcn_s_barrier();   // all reads of cur done; safe to restage
    }

    // -------- epilogue: LDS transpose -> full-line dwordx4 dist stores -------
    // Per-wave private slice: 64 rows x 40 floats (stride 40 = 160B). The
    // trailing loop barrier above guarantees all waves' step-7 ds_reads are
    // done before FL writes reuse the staging LDS.
    float* FL = (float*)(&lds[0][0][0][0]) + wid * 2560;   // 10240 B per wave

    float bs[8];
    int   bc[8];
    #pragma unroll
    for (int c = 0; c < 8; ++c) { bs[c] = FLT_MAX; bc[c] = 0; }

    #pragma unroll
    for (int h = 0; h < 2; ++h) {
        if (h == 1) {
            asm volatile("s_waitcnt lgkmcnt(0)" ::: "memory");  // half-0 reads done
            __builtin_amdgcn_sched_barrier(0);
        }
        // scatter this half's acc (cols 32h..32h+31) into FL
        #pragma unroll
        for (int mf = 0; mf < 4; ++mf)
            #pragma unroll
            for (int reg = 0; reg < 4; ++reg)
                #pragma unroll
                for (int n2 = 0; n2 < 2; ++n2) {
                    int row = mf * 16 + kg * 4 + reg;
                    FL[row * 40 + n2 * 16 + lr] = acc[mf][2 * h + n2][reg];
                }
        asm volatile("s_waitcnt lgkmcnt(0)" ::: "memory");      // writes visible
        __builtin_amdgcn_sched_barrier(0);
        // gather transposed: lane holds 4 CONSECUTIVE cols of one row
        #pragma unroll
        for (int c = 0; c < 8; ++c) {
            int row = 8 * c + rl;
            f32x4 xy = *(const f32x4*)&FL[row * 40 + q * 4];
            int t  = t0 + wm * 64 + row;
            int gc = c0 + wn * 64 + 32 * h + q * 4;
            f32x4 d;
            #pragma unroll
            for (int j = 0; j < 4; ++j) {
                float sq = fmaxf(tx2p[c] + e2p[h][j] - 2.0f * xy[j], 0.0f);
                d[j] = -sqrtf(sq);
                if (sq < bs[c]) { bs[c] = sq; bc[c] = gc + j; }   // ascending cols: first wins
            }
            // 8 consecutive lanes cover one row: 128B full-line aligned segment
            __builtin_nontemporal_store(d, (f32x4*)(dist + (size_t)t * CODES + gc));
        }
    }

    // row-argmin: reduce across the 8 lanes of each row group, then atomicMin
    #pragma unroll
    for (int c = 0; c < 8; ++c) {
        float s = bs[c];
        int   b = bc[c];
        #pragma unroll
        for (int m = 1; m <= 4; m <<= 1) {
            float os = __shfl_xor(s, m);
            int   ob = __shfl_xor(b, m);
            if (os < s || (os == s && ob < b)) { s = os; b = ob; }
        }
        if ((l & 7) == 0) {
            int t = t0 + wm * 64 + 8 * c + rl;
            unsigned long long key = ((unsigned long long)__float_as_uint(s) << 32) | (unsigned)b;
            atomicMin(keys + t, key);
        }
    }
}

// -------- quantize gather + ind write + count: one wave per TWO tokens -------
__global__ void k_qcount(const float* __restrict__ embed, const unsigned long long* __restrict__ keys,
                         float* __restrict__ q, float* __restrict__ ind_f, int* __restrict__ cnt) {
    int gid  = blockIdx.x * blockDim.x + threadIdx.x;
    int wv   = gid >> 6;
    int lane = threadIdx.x & 63;
    int w0 = wv * 2;
    if (w0 >= N_TOK) return;
    int c0 = (int)(keys[w0] & 0xFFFFFFFFULL);
    int c1 = (int)(keys[w0 + 1] & 0xFFFFFFFFULL);
    f32x4 e0 = reinterpret_cast<const f32x4*>(embed + (size_t)c0 * DIM)[lane];
    f32x4 e1 = reinterpret_cast<const f32x4*>(embed + (size_t)c1 * DIM)[lane];
    __builtin_nontemporal_store(e0, reinterpret_cast<f32x4*>(q + (size_t)w0 * DIM) + lane);
    __builtin_nontemporal_store(e1, reinterpret_cast<f32x4*>(q + (size_t)(w0 + 1) * DIM) + lane);
    if (lane == 0) {
        ind_f[w0] = (float)c0;
        ind_f[w0 + 1] = (float)c1;
        atomicAdd(cnt + c0, 1);
        atomicAdd(cnt + c1, 1);
    }
}

// ---------------- scan: offsets + new_cluster_size + smoothed (fused fin1) ---
__global__ void k_scan(const int* __restrict__ cnt, const float* __restrict__ cs,
                       int* __restrict__ offsets, float* __restrict__ out_ncs,
                       float* __restrict__ smoothed) {
    __shared__ int red[256];
    __shared__ float fred[256];
    __shared__ float s_total;
    int t = threadIdx.x;
    int c8[8];
    int own = 0;
    float ncs8[8];
    float fpart = 0.f;
    #pragma unroll
    for (int r = 0; r < 8; ++r) {
        int c = t * 8 + r;
        int v = cnt[c];
        c8[r] = v;
        own += v;
        float nn = cs[c] * DECAY + (float)v * (1.0f - DECAY);
        out_ncs[c] = nn;
        ncs8[r] = nn;
        fpart += nn;
    }
    red[t] = own;
    fred[t] = fpart;
    __syncthreads();
    for (int d = 1; d < 256; d <<= 1) {
        int v = (t >= d) ? red[t - d] : 0;
        __syncthreads();
        red[t] += v;
        __syncthreads();
    }
    for (int s = 128; s >= 1; s >>= 1) {
        if (t < s) fred[t] += fred[t + s];
        __syncthreads();
    }
    if (t == 0) s_total = fred[0];
    __syncthreads();
    int base = red[t] - own;
    float total = s_total;
    float denom = total + (float)CODES * EPSV;
    #pragma unroll
    for (int r = 0; r < 8; ++r) {
        int c = t * 8 + r;
        offsets[c] = base;
        base += c8[r];
        smoothed[c] = (ncs8[r] + EPSV) / denom * total;
    }
}

// ---------------- scatter token ids into per-code buckets --------------------
__global__ void k_scatter(const unsigned long long* __restrict__ keys,
                          const int* __restrict__ offsets, int* __restrict__ cursor,
                          int* __restrict__ list) {
    int t = blockIdx.x * blockDim.x + threadIdx.x;
    if (t >= N_TOK) return;
    int c = (int)(keys[t] & 0xFFFFFFFFULL);
    int pos = atomicAdd(cursor + c, 1);
    list[offsets[c] + pos] = t;
}

// ---------------- per-code sum of x rows + fused fin2 ------------------------
// 16 waves/block; each wave processes 8 consecutive list entries per iteration
// (8 index loads issue together -> 8 independent row gathers in flight),
// stride 128. Straggler bucket cost amortized a further 2x vs r14's 4-batch.
__global__ void k_esum(const float* __restrict__ x, const int* __restrict__ cnt,
                       const int* __restrict__ offsets, const int* __restrict__ list,
                       const float* __restrict__ ea, const float* __restrict__ smoothed,
                       float* __restrict__ out_nea, float* __restrict__ out_nemb) {
    __shared__ f32x4 part[16][64];
    int c    = blockIdx.x;
    int tid  = threadIdx.x;
    int w    = tid >> 6;          // 0..15
    int lane = tid & 63;
    int n    = cnt[c];
    int off  = offsets[c];
    f32x4 s = (f32x4){0.f, 0.f, 0.f, 0.f};
    for (int i = w * 8; i < n; i += 128) {
        #pragma unroll
        for (int j = 0; j < 8; ++j) {
            if (i + j < n) {
                int t = list[off + i + j];
                s += reinterpret_cast<const f32x4*>(x + (size_t)t * DIM)[lane];
            }
        }
    }
    part[w][lane] = s;
    __syncthreads();
    if (w == 0) {
        f32x4 tot = part[0][lane];
        #pragma unroll
        for (int p = 1; p < 16; ++p) tot += part[p][lane];
        size_t idx = (size_t)c * DIM + lane * 4;
        f32x4 ea4 = *reinterpret_cast<const f32x4*>(ea + idx);
        f32x4 nea;
        float inv = 1.0f / smoothed[c];
        #pragma unroll
        for (int j = 0; j < 4; ++j) nea[j] = ea4[j] * DECAY + tot[j] * (1.0f - DECAY);
        *reinterpret_cast<f32x4*>(out_nea + idx) = nea;
        f32x4 nemb;
        #pragma unroll
        for (int j = 0; j < 4; ++j) nemb[j] = nea[j] * inv;
        *reinterpret_cast<f32x4*>(out_nemb + idx) = nemb;
    }
}

extern "C" void kernel_launch(void* const* d_in, const int* in_sizes, int n_in,
                              void* d_out, int out_size, void* d_ws, size_t ws_size,
                              hipStream_t stream) {
    const float* x     = (const float*)d_in[0];
    const float* embed = (const float*)d_in[1];
    const float* eavg  = (const float*)d_in[2];
    const float* csz   = (const float*)d_in[3];
    float* out = (float*)d_out;
    char*  wsb = (char*)d_ws;

    unsigned long long* keys = (unsigned long long*)(wsb + WSB_KEYS);
    int*            cnt  = (int*)(wsb + WSB_CNT);     // cnt+cur contiguous 16KB
    int*            cur  = (int*)(wsb + WSB_CUR);
    int*            off  = (int*)(wsb + WSB_OFF);
    int*            list = (int*)(wsb + WSB_LIST);
    unsigned short* ehi  = (unsigned short*)(wsb + WSB_EHI);
    unsigned short* elo  = (unsigned short*)(wsb + WSB_ELO);
    float*          x2   = (float*)(wsb + WSB_X2);
    float*          e2   = (float*)(wsb + WSB_E2);
    float*          smoo = (float*)(wsb + WSB_SMOO);

    // x hi/lo staged in the quantize output region (same byte size); k_qcount
    // overwrites it AFTER k_main has consumed it (stream-ordered).
    unsigned short* xhi = (unsigned short*)(out + OUT_Q);
    unsigned short* xlo = xhi + (size_t)N_TOK * DIM;

    k_prep<<<(N_TOK + CODES) * 32 / 256, 256, 0, stream>>>(
        x, embed, xhi, xlo, ehi, elo, x2, e2, keys, cnt);

    k_main<<<(CODES / 128) * (N_TOK / 128), 256, 0, stream>>>(
        xhi, xlo, ehi, elo, x2, e2, out + OUT_DIST, keys);

    k_qcount<<<N_TOK * 32 / 256, 256, 0, stream>>>(embed, keys, out + OUT_Q,
                                                   out + OUT_IND, cnt);
    k_scan<<<1, 256, 0, stream>>>(cnt, csz, off, out + OUT_NCS, smoo);
    k_scatter<<<N_TOK / 256, 256, 0, stream>>>(keys, off, cur, list);
    k_esum<<<CODES, 1024, 0, stream>>>(x, cnt, off, list, eavg, smoo,
                                       out + OUT_NEA, out + OUT_NEMB);
}